// Round 1
// baseline (2874.503 us; speedup 1.0000x reference)
//
#include <hip/hip_runtime.h>

#define HDIM 64
#define F1 256
#define F3 192
#define FH 128

// ---------------- init: deg=1, zero accumulators ----------------
__global__ __launch_bounds__(256) void init_kernel(float* deg, float* pooled,
                                                   float* mcnt, int* cnt, int N) {
  int i = blockIdx.x * blockDim.x + threadIdx.x;
  int stride = gridDim.x * blockDim.x;
  for (int j = i; j < N; j += stride) deg[j] = 1.0f;
  if (i < F3) pooled[i] = 0.0f;
  if (i == 0) { *mcnt = 0.0f; *cnt = 0; }
}

// ---------------- degree accumulation over masked edges ----------------
__global__ __launch_bounds__(256) void deg_kernel(const int* __restrict__ ei,
                                                  const int* __restrict__ nt,
                                                  float* __restrict__ deg, int E) {
  int i = blockIdx.x * blockDim.x + threadIdx.x;
  int stride = gridDim.x * blockDim.x;
  for (int e = i; e < E; e += stride) {
    int s = ei[e], d = ei[E + e];
    if (nt[s] == 0 && nt[d] == 0) atomicAdd(&deg[d], 1.0f);
  }
}

// ---------------- deg -> dinv, and count masked nodes ----------------
__global__ __launch_bounds__(256) void dinv_kernel(float* __restrict__ deg,
                                                   const int* __restrict__ nt,
                                                   float* __restrict__ mcnt, int N) {
  int i = blockIdx.x * blockDim.x + threadIdx.x;
  int stride = gridDim.x * blockDim.x;
  for (int j = i; j < N; j += stride) {
    deg[j] = 1.0f / sqrtf(deg[j]);
    unsigned long long b = __ballot(nt[j] == 0);
    if ((threadIdx.x & 63) == 0) atomicAdd(mcnt, (float)__popcll(b));
  }
}

// ---------------- compact active edges ----------------
__global__ __launch_bounds__(256) void compact_kernel(const int* __restrict__ ei,
                                                      const int* __restrict__ nt,
                                                      const float* __restrict__ dinv,
                                                      int* __restrict__ cnt,
                                                      int* __restrict__ asrc,
                                                      int* __restrict__ adst,
                                                      float* __restrict__ anorm, int E) {
  int i = blockIdx.x * blockDim.x + threadIdx.x;
  int stride = gridDim.x * blockDim.x;
  for (int e = i; e < E; e += stride) {
    int s = ei[e], d = ei[E + e];
    if (nt[s] == 0 && nt[d] == 0) {
      int idx = atomicAdd(cnt, 1);
      asrc[idx] = s;
      adst[idx] = d;
      anorm[idx] = dinv[s] * dinv[d];
    }
  }
}

// ---------------- z = emb[x] ----------------
__global__ __launch_bounds__(256) void embed_kernel(const int* __restrict__ x,
                                                    const float* __restrict__ emb,
                                                    float* __restrict__ A, int N) {
  int i = blockIdx.x * blockDim.x + threadIdx.x;
  int stride = gridDim.x * blockDim.x;
  int total = N * (HDIM / 4);
  for (int j = i; j < total; j += stride) {
    int row = j >> 4;
    int c = (j & 15) * 4;
    int xr = x[row];
    *(float4*)&A[(size_t)row * HDIM + c] = *(const float4*)&emb[(size_t)xr * HDIM + c];
  }
}

// ---------------- fp32 GEMM: Out[N,FOUT] = (RELU?)Z[N,FIN] @ W[FIN,FOUT] ---------
// block tile 128 rows x 64 cols, 256 threads, 8x4 micro-tile per thread
template <int FIN, int FOUT, bool RELU>
__global__ __launch_bounds__(256) void gemm_kernel(const float* __restrict__ Z,
                                                   const float* __restrict__ W,
                                                   float* __restrict__ Out, int N) {
  __shared__ float ZL[128][68];  // +4 pad: g-groups land on distinct banks
  __shared__ float WL[64][64];
  const int tid = threadIdx.x;
  const int c16 = tid & 15;  // col group: cols 4*c16..4*c16+3
  const int g = tid >> 4;    // row group: rows g + 16*j
  const int r0 = blockIdx.x * 128;
  const int c0 = blockIdx.y * 64;
  float acc[8][4];
#pragma unroll
  for (int j = 0; j < 8; ++j)
#pragma unroll
    for (int q = 0; q < 4; ++q) acc[j][q] = 0.0f;

  for (int k0 = 0; k0 < FIN; k0 += 64) {
#pragma unroll
    for (int p = 0; p < 8; ++p) {
      int q = tid + 256 * p;  // 0..2047 -> 128x16 float4
      int zr = q >> 4;
      int zc = (q & 15) * 4;
      int grow = r0 + zr;
      float4 v = {0.f, 0.f, 0.f, 0.f};
      if (grow < N) v = *(const float4*)&Z[(size_t)grow * FIN + k0 + zc];
      if (RELU) {
        v.x = fmaxf(v.x, 0.f); v.y = fmaxf(v.y, 0.f);
        v.z = fmaxf(v.z, 0.f); v.w = fmaxf(v.w, 0.f);
      }
      *(float4*)&ZL[zr][zc] = v;
    }
#pragma unroll
    for (int p = 0; p < 4; ++p) {
      int q = tid + 256 * p;  // 0..1023 -> 64x16 float4
      int kr = q >> 4;
      int wc = (q & 15) * 4;
      *(float4*)&WL[kr][wc] = *(const float4*)&W[(size_t)(k0 + kr) * FOUT + c0 + wc];
    }
    __syncthreads();
#pragma unroll
    for (int k = 0; k < 64; k += 4) {
      float4 wv0 = *(const float4*)&WL[k + 0][4 * c16];
      float4 wv1 = *(const float4*)&WL[k + 1][4 * c16];
      float4 wv2 = *(const float4*)&WL[k + 2][4 * c16];
      float4 wv3 = *(const float4*)&WL[k + 3][4 * c16];
#pragma unroll
      for (int j = 0; j < 8; ++j) {
        float4 zv = *(const float4*)&ZL[g + 16 * j][k];
        acc[j][0] += zv.x * wv0.x + zv.y * wv1.x + zv.z * wv2.x + zv.w * wv3.x;
        acc[j][1] += zv.x * wv0.y + zv.y * wv1.y + zv.z * wv2.y + zv.w * wv3.y;
        acc[j][2] += zv.x * wv0.z + zv.y * wv1.z + zv.z * wv2.z + zv.w * wv3.z;
        acc[j][3] += zv.x * wv0.w + zv.y * wv1.w + zv.z * wv2.w + zv.w * wv3.w;
      }
    }
    __syncthreads();
  }
#pragma unroll
  for (int j = 0; j < 8; ++j) {
    int row = r0 + g + 16 * j;
    if (row < N) {
      float4 o = {acc[j][0], acc[j][1], acc[j][2], acc[j][3]};
      *(float4*)&Out[(size_t)row * FOUT + c0 + 4 * c16] = o;
    }
  }
}

// ---------------- Agg = selfnorm*HW + bias ----------------
template <int FOUT>
__global__ __launch_bounds__(256) void agginit_kernel(const float* __restrict__ HW,
                                                      const float* __restrict__ dinv,
                                                      const float* __restrict__ bias,
                                                      float* __restrict__ Agg, int N) {
  const int C4 = FOUT / 4;
  long long i = (long long)blockIdx.x * blockDim.x + threadIdx.x;
  long long total = (long long)N * C4;
  long long stride = (long long)gridDim.x * blockDim.x;
  for (; i < total; i += stride) {
    int row = (int)(i / C4);
    int c = (int)(i % C4) * 4;
    float di = dinv[row];
    float sn = di * di;
    float4 v = *(const float4*)&HW[(size_t)row * FOUT + c];
    float4 bb = *(const float4*)&bias[c];
    float4 o = {sn * v.x + bb.x, sn * v.y + bb.y, sn * v.z + bb.z, sn * v.w + bb.w};
    *(float4*)&Agg[(size_t)row * FOUT + c] = o;
  }
}

// ---------------- scatter: Agg[dst] += norm * HW[src], one wave per edge ---------
template <int FOUT>
__global__ __launch_bounds__(256) void scatter_kernel(const float* __restrict__ HW,
                                                      float* __restrict__ Agg,
                                                      const int* __restrict__ asrc,
                                                      const int* __restrict__ adst,
                                                      const float* __restrict__ anorm,
                                                      const int* __restrict__ cnt) {
  const int lane = threadIdx.x & 63;
  const int wid = (int)((blockIdx.x * blockDim.x + threadIdx.x) >> 6);
  const int nw = (int)((gridDim.x * blockDim.x) >> 6);
  const int n = *cnt;
  const bool act = (lane * 4) < FOUT;
  for (int e = wid; e < n; e += nw) {
    int s = asrc[e], d = adst[e];
    float w = anorm[e];
    if (act) {
      float4 v = *(const float4*)&HW[(size_t)s * FOUT + 4 * lane];
      float* ap = &Agg[(size_t)d * FOUT + 4 * lane];
      atomicAdd(ap + 0, w * v.x);
      atomicAdd(ap + 1, w * v.y);
      atomicAdd(ap + 2, w * v.z);
      atomicAdd(ap + 3, w * v.w);
    }
  }
}

// ---------------- masked mean-pool partials (relu applied on read) ----------------
__global__ __launch_bounds__(256) void pool_kernel(const float* __restrict__ Z,
                                                   const int* __restrict__ nt,
                                                   float* __restrict__ pooled, int N) {
  int t = threadIdx.x;
  float acc = 0.0f;
  for (int r = blockIdx.x; r < N; r += gridDim.x) {
    if (nt[r] == 0 && t < F3) acc += fmaxf(Z[(size_t)r * F3 + t], 0.f);
  }
  if (t < F3) atomicAdd(&pooled[t], acc);
}

// ---------------- phead = bh1 + (pooled/mcnt) @ Wh1[0:192,:] ----------------
__global__ __launch_bounds__(128) void phead_kernel(const float* __restrict__ pooled,
                                                    const float* __restrict__ mcnt,
                                                    const float* __restrict__ Wh1,
                                                    const float* __restrict__ bh1,
                                                    float* __restrict__ phead) {
  int t = threadIdx.x;  // 128 threads
  float inv = 1.0f / *mcnt;
  float acc = bh1[t];
  for (int k = 0; k < F3; ++k) acc += pooled[k] * inv * Wh1[k * FH + t];
  phead[t] = acc;
}

// ---------------- head: per-node emb@Wh1[192:256] + phead -> relu -> BN -> @Wh2 ----
__global__ __launch_bounds__(256) void head_kernel(const int* __restrict__ x,
                                                   const float* __restrict__ emb,
                                                   const float* __restrict__ Wh1,
                                                   const float* __restrict__ phead,
                                                   const float* __restrict__ gamma,
                                                   const float* __restrict__ beta,
                                                   const float* __restrict__ Wh2,
                                                   const float* __restrict__ bh2,
                                                   float* __restrict__ out, int N) {
  const int lane = threadIdx.x & 63;
  const int wid = (int)((blockIdx.x * blockDim.x + threadIdx.x) >> 6);
  const int nw = (int)((gridDim.x * blockDim.x) >> 6);
  const float bninv = 1.0f / sqrtf(1.0f + 1e-5f);
  const float ph0 = phead[lane], ph1 = phead[64 + lane];
  const float ga0 = gamma[lane] * bninv, ga1 = gamma[64 + lane] * bninv;
  const float be0 = beta[lane], be1 = beta[64 + lane];
  const float w20 = Wh2[lane], w21 = Wh2[64 + lane];
  const float bias2 = bh2[0];
  for (int r = wid; r < N; r += nw) {
    int xr = x[r];
    float ev = emb[(size_t)xr * HDIM + lane];
    float a0 = 0.f, a1 = 0.f;
#pragma unroll
    for (int k = 0; k < HDIM; ++k) {
      float zk = __shfl(ev, k);
      a0 += zk * Wh1[(size_t)(F3 + k) * FH + lane];
      a1 += zk * Wh1[(size_t)(F3 + k) * FH + 64 + lane];
    }
    float h0 = fmaxf(ph0 + a0, 0.f) * ga0 + be0;
    float h1 = fmaxf(ph1 + a1, 0.f) * ga1 + be1;
    float contrib = h0 * w20 + h1 * w21;
#pragma unroll
    for (int off = 32; off; off >>= 1) contrib += __shfl_xor(contrib, off);
    if (lane == 0) out[r] = contrib + bias2;
  }
}

extern "C" void kernel_launch(void* const* d_in, const int* in_sizes, int n_in,
                              void* d_out, int out_size, void* d_ws, size_t ws_size,
                              hipStream_t stream) {
  const int N = in_sizes[0];
  const int E = in_sizes[1] / 2;

  const int* x = (const int*)d_in[0];
  const int* ei = (const int*)d_in[1];
  const int* nt = (const int*)d_in[2];
  const float* emb = (const float*)d_in[3];
  const float* W1 = (const float*)d_in[4];
  const float* b1 = (const float*)d_in[5];
  const float* W2 = (const float*)d_in[6];
  const float* b2 = (const float*)d_in[7];
  const float* W3 = (const float*)d_in[8];
  const float* b3 = (const float*)d_in[9];
  const float* Wh1 = (const float*)d_in[10];
  const float* bh1 = (const float*)d_in[11];
  const float* gamma = (const float*)d_in[12];
  const float* beta = (const float*)d_in[13];
  const float* Wh2 = (const float*)d_in[14];
  const float* bh2 = (const float*)d_in[15];
  float* out = (float*)d_out;

  // workspace layout (floats)
  float* ws = (float*)d_ws;
  float* A = ws;                         // N*256 (z / agg)
  float* B = A + (size_t)N * 256;        // N*256 (hw)
  float* dinv = B + (size_t)N * 256;     // N (deg then dinv)
  float* anorm = dinv + N;               // E
  int* asrc = (int*)(anorm + E);         // E
  int* adst = asrc + E;                  // E
  float* pooled = (float*)(adst + E);    // 192
  float* phead = pooled + F3;            // 128
  float* mcnt = phead + FH;              // 1
  int* cnt = (int*)(mcnt + 1);           // 1
  (void)ws_size; (void)n_in; (void)out_size;

  const int rowBlocks = (N + 127) / 128;

  init_kernel<<<256, 256, 0, stream>>>(dinv, pooled, mcnt, cnt, N);
  deg_kernel<<<1024, 256, 0, stream>>>(ei, nt, dinv, E);
  dinv_kernel<<<256, 256, 0, stream>>>(dinv, nt, mcnt, N);
  compact_kernel<<<1024, 256, 0, stream>>>(ei, nt, dinv, cnt, asrc, adst, anorm, E);
  embed_kernel<<<1024, 256, 0, stream>>>(x, emb, A, N);

  // layer 1: z(N,64) -> hw B(N,256); agg in A
  gemm_kernel<HDIM, F1, false><<<dim3(rowBlocks, F1 / 64), 256, 0, stream>>>(A, W1, B, N);
  agginit_kernel<F1><<<2048, 256, 0, stream>>>(B, dinv, b1, A, N);
  scatter_kernel<F1><<<4096, 256, 0, stream>>>(B, A, asrc, adst, anorm, cnt);

  // layer 2: z1 = relu(A) (fused into load)
  gemm_kernel<F1, F1, true><<<dim3(rowBlocks, F1 / 64), 256, 0, stream>>>(A, W2, B, N);
  agginit_kernel<F1><<<2048, 256, 0, stream>>>(B, dinv, b2, A, N);
  scatter_kernel<F1><<<4096, 256, 0, stream>>>(B, A, asrc, adst, anorm, cnt);

  // layer 3: z2 = relu(A)
  gemm_kernel<F1, F3, true><<<dim3(rowBlocks, F3 / 64), 256, 0, stream>>>(A, W3, B, N);
  agginit_kernel<F3><<<2048, 256, 0, stream>>>(B, dinv, b3, A, N);
  scatter_kernel<F3><<<4096, 256, 0, stream>>>(B, A, asrc, adst, anorm, cnt);

  // pooled mean over masked nodes (relu fused), then head
  pool_kernel<<<512, 256, 0, stream>>>(A, nt, pooled, N);
  phead_kernel<<<1, 128, 0, stream>>>(pooled, mcnt, Wh1, bh1, phead);
  head_kernel<<<768, 256, 0, stream>>>(x, emb, Wh1, phead, gamma, beta, Wh2, bh2, out, N);
}

// Round 2
// 1071.016 us; speedup vs baseline: 2.6839x; 2.6839x over previous
//
#include <hip/hip_runtime.h>

#define HDIM 64
#define F1 256
#define F3 192
#define FH 128

// ---------------- init: zero counts, pooled, mcnt ----------------
__global__ __launch_bounds__(256) void init_kernel(int* counts, float* pooled,
                                                   float* mcnt, int N) {
  int i = blockIdx.x * blockDim.x + threadIdx.x;
  int stride = gridDim.x * blockDim.x;
  for (int j = i; j < N; j += stride) counts[j] = 0;
  if (i < F3) pooled[i] = 0.0f;
  if (i == 0) *mcnt = 0.0f;
}

// ---------------- masked in-degree counts (int atomics, 50k counters) -----------
__global__ __launch_bounds__(256) void count_kernel(const int* __restrict__ ei,
                                                    const int* __restrict__ nt,
                                                    int* __restrict__ counts, int E) {
  int i = blockIdx.x * blockDim.x + threadIdx.x;
  int stride = gridDim.x * blockDim.x;
  for (int e = i; e < E; e += stride) {
    int s = ei[e], d = ei[E + e];
    if (nt[s] == 0 && nt[d] == 0) atomicAdd(&counts[d], 1);
  }
}

// ---------------- counts -> dinv, count masked nodes ----------------
__global__ __launch_bounds__(256) void dinv_kernel(const int* __restrict__ counts,
                                                   const int* __restrict__ nt,
                                                   float* __restrict__ dinv,
                                                   float* __restrict__ mcnt, int N) {
  int i = blockIdx.x * blockDim.x + threadIdx.x;
  int stride = gridDim.x * blockDim.x;
  for (int j = i; j < N; j += stride) {
    dinv[j] = rsqrtf(1.0f + (float)counts[j]);
    unsigned long long b = __ballot(nt[j] == 0);
    if ((threadIdx.x & 63) == 0) atomicAdd(mcnt, (float)__popcll(b));
  }
}

// ---------------- exclusive scan of counts -> rowstart[N+1], fill=rowstart -------
__global__ __launch_bounds__(1024) void scan_kernel(const int* __restrict__ counts,
                                                    int* __restrict__ rowstart,
                                                    int* __restrict__ fill, int N) {
  __shared__ int sdata[1024];
  __shared__ int running;
  if (threadIdx.x == 0) running = 0;
  __syncthreads();
  int nch = (N + 1023) / 1024;
  for (int ch = 0; ch < nch; ++ch) {
    int base = running;  // valid: sync'ed at end of previous iteration
    int i = ch * 1024 + threadIdx.x;
    int v = (i < N) ? counts[i] : 0;
    sdata[threadIdx.x] = v;
    __syncthreads();
#pragma unroll
    for (int off = 1; off < 1024; off <<= 1) {
      int t = (threadIdx.x >= off) ? sdata[threadIdx.x - off] : 0;
      __syncthreads();
      sdata[threadIdx.x] += t;
      __syncthreads();
    }
    int excl = sdata[threadIdx.x] - v;
    if (i < N) {
      rowstart[i] = base + excl;
      fill[i] = base + excl;
    }
    int tot = sdata[1023];
    __syncthreads();
    if (threadIdx.x == 0) running = base + tot;
    __syncthreads();
  }
  if (threadIdx.x == 0) rowstart[N] = running;
}

// ---------------- bucket active edges by dst ----------------
__global__ __launch_bounds__(256) void fill_kernel(const int* __restrict__ ei,
                                                   const int* __restrict__ nt,
                                                   const float* __restrict__ dinv,
                                                   int* __restrict__ fill,
                                                   int* __restrict__ csr_src,
                                                   float* __restrict__ csr_w, int E) {
  int i = blockIdx.x * blockDim.x + threadIdx.x;
  int stride = gridDim.x * blockDim.x;
  for (int e = i; e < E; e += stride) {
    int s = ei[e], d = ei[E + e];
    if (nt[s] == 0 && nt[d] == 0) {
      int pos = atomicAdd(&fill[d], 1);
      csr_src[pos] = s;
      csr_w[pos] = dinv[s] * dinv[d];
    }
  }
}

// ---------------- z = emb[x] ----------------
__global__ __launch_bounds__(256) void embed_kernel(const int* __restrict__ x,
                                                    const float* __restrict__ emb,
                                                    float* __restrict__ A, int N) {
  int i = blockIdx.x * blockDim.x + threadIdx.x;
  int stride = gridDim.x * blockDim.x;
  int total = N * (HDIM / 4);
  for (int j = i; j < total; j += stride) {
    int row = j >> 4;
    int c = (j & 15) * 4;
    int xr = x[row];
    *(float4*)&A[(size_t)row * HDIM + c] = *(const float4*)&emb[(size_t)xr * HDIM + c];
  }
}

// ---------------- fp32 GEMM: Out[N,FOUT] = (RELU?)Z[N,FIN] @ W[FIN,FOUT] ---------
template <int FIN, int FOUT, bool RELU>
__global__ __launch_bounds__(256) void gemm_kernel(const float* __restrict__ Z,
                                                   const float* __restrict__ W,
                                                   float* __restrict__ Out, int N) {
  __shared__ float ZL[128][68];
  __shared__ float WL[64][64];
  const int tid = threadIdx.x;
  const int c16 = tid & 15;
  const int g = tid >> 4;
  const int r0 = blockIdx.x * 128;
  const int c0 = blockIdx.y * 64;
  float acc[8][4];
#pragma unroll
  for (int j = 0; j < 8; ++j)
#pragma unroll
    for (int q = 0; q < 4; ++q) acc[j][q] = 0.0f;

  for (int k0 = 0; k0 < FIN; k0 += 64) {
#pragma unroll
    for (int p = 0; p < 8; ++p) {
      int q = tid + 256 * p;
      int zr = q >> 4;
      int zc = (q & 15) * 4;
      int grow = r0 + zr;
      float4 v = {0.f, 0.f, 0.f, 0.f};
      if (grow < N) v = *(const float4*)&Z[(size_t)grow * FIN + k0 + zc];
      if (RELU) {
        v.x = fmaxf(v.x, 0.f); v.y = fmaxf(v.y, 0.f);
        v.z = fmaxf(v.z, 0.f); v.w = fmaxf(v.w, 0.f);
      }
      *(float4*)&ZL[zr][zc] = v;
    }
#pragma unroll
    for (int p = 0; p < 4; ++p) {
      int q = tid + 256 * p;
      int kr = q >> 4;
      int wc = (q & 15) * 4;
      *(float4*)&WL[kr][wc] = *(const float4*)&W[(size_t)(k0 + kr) * FOUT + c0 + wc];
    }
    __syncthreads();
#pragma unroll
    for (int k = 0; k < 64; k += 4) {
      float4 wv0 = *(const float4*)&WL[k + 0][4 * c16];
      float4 wv1 = *(const float4*)&WL[k + 1][4 * c16];
      float4 wv2 = *(const float4*)&WL[k + 2][4 * c16];
      float4 wv3 = *(const float4*)&WL[k + 3][4 * c16];
#pragma unroll
      for (int j = 0; j < 8; ++j) {
        float4 zv = *(const float4*)&ZL[g + 16 * j][k];
        acc[j][0] += zv.x * wv0.x + zv.y * wv1.x + zv.z * wv2.x + zv.w * wv3.x;
        acc[j][1] += zv.x * wv0.y + zv.y * wv1.y + zv.z * wv2.y + zv.w * wv3.y;
        acc[j][2] += zv.x * wv0.z + zv.y * wv1.z + zv.z * wv2.z + zv.w * wv3.z;
        acc[j][3] += zv.x * wv0.w + zv.y * wv1.w + zv.z * wv2.w + zv.w * wv3.w;
      }
    }
    __syncthreads();
  }
#pragma unroll
  for (int j = 0; j < 8; ++j) {
    int row = r0 + g + 16 * j;
    if (row < N) {
      float4 o = {acc[j][0], acc[j][1], acc[j][2], acc[j][3]};
      *(float4*)&Out[(size_t)row * FOUT + c0 + 4 * c16] = o;
    }
  }
}

// ---- pull aggregation: Agg[r] = bias + selfnorm*HW[r] + sum_e w_e * HW[src_e] ----
// one wave per node; lane handles 4 contiguous features; register accumulation.
template <int FOUT>
__global__ __launch_bounds__(256) void aggregate_kernel(const float* __restrict__ HW,
                                                        const int* __restrict__ rowstart,
                                                        const int* __restrict__ csr_src,
                                                        const float* __restrict__ csr_w,
                                                        const float* __restrict__ dinv,
                                                        const float* __restrict__ bias,
                                                        float* __restrict__ Agg, int N) {
  const int lane = threadIdx.x & 63;
  const int wid = (int)((blockIdx.x * blockDim.x + threadIdx.x) >> 6);
  const int nw = (int)((gridDim.x * blockDim.x) >> 6);
  const bool act = (4 * lane) < FOUT;
  for (int r = wid; r < N; r += nw) {
    const int e0 = rowstart[r];
    const int e1 = rowstart[r + 1];
    float4 acc = {0.f, 0.f, 0.f, 0.f};
    if (act) {
      float di = dinv[r];
      float sn = di * di;
      float4 v = *(const float4*)&HW[(size_t)r * FOUT + 4 * lane];
      float4 bb = *(const float4*)&bias[4 * lane];
      acc.x = sn * v.x + bb.x; acc.y = sn * v.y + bb.y;
      acc.z = sn * v.z + bb.z; acc.w = sn * v.w + bb.w;
    }
    for (int e = e0; e < e1; ++e) {
      int s = csr_src[e];     // wave-uniform -> scalar load
      float w = csr_w[e];
      if (act) {
        float4 v = *(const float4*)&HW[(size_t)s * FOUT + 4 * lane];
        acc.x += w * v.x; acc.y += w * v.y;
        acc.z += w * v.z; acc.w += w * v.w;
      }
    }
    if (act) *(float4*)&Agg[(size_t)r * FOUT + 4 * lane] = acc;
  }
}

// ---------------- masked mean-pool partials (relu applied on read) ----------------
__global__ __launch_bounds__(256) void pool_kernel(const float* __restrict__ Z,
                                                   const int* __restrict__ nt,
                                                   float* __restrict__ pooled, int N) {
  int t = threadIdx.x;
  float acc = 0.0f;
  for (int r = blockIdx.x; r < N; r += gridDim.x) {
    if (nt[r] == 0 && t < F3) acc += fmaxf(Z[(size_t)r * F3 + t], 0.f);
  }
  if (t < F3) atomicAdd(&pooled[t], acc);
}

// ---------------- phead = bh1 + (pooled/mcnt) @ Wh1[0:192,:] ----------------
__global__ __launch_bounds__(128) void phead_kernel(const float* __restrict__ pooled,
                                                    const float* __restrict__ mcnt,
                                                    const float* __restrict__ Wh1,
                                                    const float* __restrict__ bh1,
                                                    float* __restrict__ phead) {
  int t = threadIdx.x;
  float inv = 1.0f / *mcnt;
  float acc = bh1[t];
  for (int k = 0; k < F3; ++k) acc += pooled[k] * inv * Wh1[k * FH + t];
  phead[t] = acc;
}

// ---------------- head: per-node emb@Wh1[192:256] + phead -> relu -> BN -> @Wh2 ----
__global__ __launch_bounds__(256) void head_kernel(const int* __restrict__ x,
                                                   const float* __restrict__ emb,
                                                   const float* __restrict__ Wh1,
                                                   const float* __restrict__ phead,
                                                   const float* __restrict__ gamma,
                                                   const float* __restrict__ beta,
                                                   const float* __restrict__ Wh2,
                                                   const float* __restrict__ bh2,
                                                   float* __restrict__ out, int N) {
  const int lane = threadIdx.x & 63;
  const int wid = (int)((blockIdx.x * blockDim.x + threadIdx.x) >> 6);
  const int nw = (int)((gridDim.x * blockDim.x) >> 6);
  const float bninv = 1.0f / sqrtf(1.0f + 1e-5f);
  const float ph0 = phead[lane], ph1 = phead[64 + lane];
  const float ga0 = gamma[lane] * bninv, ga1 = gamma[64 + lane] * bninv;
  const float be0 = beta[lane], be1 = beta[64 + lane];
  const float w20 = Wh2[lane], w21 = Wh2[64 + lane];
  const float bias2 = bh2[0];
  for (int r = wid; r < N; r += nw) {
    int xr = x[r];
    float ev = emb[(size_t)xr * HDIM + lane];
    float a0 = 0.f, a1 = 0.f;
#pragma unroll
    for (int k = 0; k < HDIM; ++k) {
      float zk = __shfl(ev, k);
      a0 += zk * Wh1[(size_t)(F3 + k) * FH + lane];
      a1 += zk * Wh1[(size_t)(F3 + k) * FH + 64 + lane];
    }
    float h0 = fmaxf(ph0 + a0, 0.f) * ga0 + be0;
    float h1 = fmaxf(ph1 + a1, 0.f) * ga1 + be1;
    float contrib = h0 * w20 + h1 * w21;
#pragma unroll
    for (int off = 32; off; off >>= 1) contrib += __shfl_xor(contrib, off);
    if (lane == 0) out[r] = contrib + bias2;
  }
}

extern "C" void kernel_launch(void* const* d_in, const int* in_sizes, int n_in,
                              void* d_out, int out_size, void* d_ws, size_t ws_size,
                              hipStream_t stream) {
  const int N = in_sizes[0];
  const int E = in_sizes[1] / 2;

  const int* x = (const int*)d_in[0];
  const int* ei = (const int*)d_in[1];
  const int* nt = (const int*)d_in[2];
  const float* emb = (const float*)d_in[3];
  const float* W1 = (const float*)d_in[4];
  const float* b1 = (const float*)d_in[5];
  const float* W2 = (const float*)d_in[6];
  const float* b2 = (const float*)d_in[7];
  const float* W3 = (const float*)d_in[8];
  const float* b3 = (const float*)d_in[9];
  const float* Wh1 = (const float*)d_in[10];
  const float* bh1 = (const float*)d_in[11];
  const float* gamma = (const float*)d_in[12];
  const float* beta = (const float*)d_in[13];
  const float* Wh2 = (const float*)d_in[14];
  const float* bh2 = (const float*)d_in[15];
  float* out = (float*)d_out;

  // workspace layout
  float* ws = (float*)d_ws;
  float* A = ws;                              // N*256 (z / agg)
  float* B = A + (size_t)N * 256;             // N*256 (hw)
  float* dinv = B + (size_t)N * 256;          // N
  float* csr_w = dinv + N;                    // E
  int* csr_src = (int*)(csr_w + E);           // E
  int* counts = csr_src + E;                  // N
  int* fill = counts + N;                     // N
  int* rowstart = fill + N;                   // N+1
  float* pooled = (float*)(rowstart + N + 1); // 192
  float* phead = pooled + F3;                 // 128
  float* mcnt = phead + FH;                   // 1
  (void)ws_size; (void)n_in; (void)out_size;

  const int rowBlocks = (N + 127) / 128;
  const int aggBlocks = (N + 3) / 4;  // one wave per node

  init_kernel<<<256, 256, 0, stream>>>(counts, pooled, mcnt, N);
  count_kernel<<<1024, 256, 0, stream>>>(ei, nt, counts, E);
  dinv_kernel<<<256, 256, 0, stream>>>(counts, nt, dinv, mcnt, N);
  scan_kernel<<<1, 1024, 0, stream>>>(counts, rowstart, fill, N);
  fill_kernel<<<1024, 256, 0, stream>>>(ei, nt, dinv, fill, csr_src, csr_w, E);
  embed_kernel<<<1024, 256, 0, stream>>>(x, emb, A, N);

  // layer 1
  gemm_kernel<HDIM, F1, false><<<dim3(rowBlocks, F1 / 64), 256, 0, stream>>>(A, W1, B, N);
  aggregate_kernel<F1><<<aggBlocks, 256, 0, stream>>>(B, rowstart, csr_src, csr_w, dinv, b1, A, N);

  // layer 2
  gemm_kernel<F1, F1, true><<<dim3(rowBlocks, F1 / 64), 256, 0, stream>>>(A, W2, B, N);
  aggregate_kernel<F1><<<aggBlocks, 256, 0, stream>>>(B, rowstart, csr_src, csr_w, dinv, b2, A, N);

  // layer 3
  gemm_kernel<F1, F3, true><<<dim3(rowBlocks, F3 / 64), 256, 0, stream>>>(A, W3, B, N);
  aggregate_kernel<F3><<<aggBlocks, 256, 0, stream>>>(B, rowstart, csr_src, csr_w, dinv, b3, A, N);

  // pool + head
  pool_kernel<<<512, 256, 0, stream>>>(A, nt, pooled, N);
  phead_kernel<<<1, 128, 0, stream>>>(pooled, mcnt, Wh1, bh1, phead);
  head_kernel<<<768, 256, 0, stream>>>(x, emb, Wh1, phead, gamma, beta, Wh2, bh2, out, N);
}

// Round 3
// 510.031 us; speedup vs baseline: 5.6359x; 2.0999x over previous
//
#include <hip/hip_runtime.h>

#define HDIM 64
#define F1 256
#define F3 192
#define FH 128

typedef unsigned short u16;
typedef __attribute__((ext_vector_type(8))) short short8;
typedef __attribute__((ext_vector_type(4))) float f32x4;
typedef __attribute__((ext_vector_type(2))) unsigned int uint2v;

// fp32 -> bf16(hi) + bf16(lo), both RNE
__device__ __forceinline__ void split2(float v, u16& h, u16& l) {
  unsigned u = __float_as_uint(v);
  unsigned r = u + 0x7FFFu + ((u >> 16) & 1u);
  h = (u16)(r >> 16);
  float fh = __uint_as_float(((unsigned)h) << 16);
  float res = v - fh;
  unsigned u2 = __float_as_uint(res);
  unsigned r2 = u2 + 0x7FFFu + ((u2 >> 16) & 1u);
  l = (u16)(r2 >> 16);
}

// ---------------- init ----------------
__global__ __launch_bounds__(256) void init_kernel(int* counts, float* pooled,
                                                   float* mcnt, int N) {
  int i = blockIdx.x * blockDim.x + threadIdx.x;
  int stride = gridDim.x * blockDim.x;
  for (int j = i; j < N; j += stride) counts[j] = 0;
  if (i < F3) pooled[i] = 0.0f;
  if (i == 0) *mcnt = 0.0f;
}

// ---------------- masked in-degree ----------------
__global__ __launch_bounds__(256) void count_kernel(const int* __restrict__ ei,
                                                    const int* __restrict__ nt,
                                                    int* __restrict__ counts, int E) {
  int i = blockIdx.x * blockDim.x + threadIdx.x;
  int stride = gridDim.x * blockDim.x;
  for (int e = i; e < E; e += stride) {
    int s = ei[e], d = ei[E + e];
    if (nt[s] == 0 && nt[d] == 0) atomicAdd(&counts[d], 1);
  }
}

// ---------------- counts -> dinv, masked count ----------------
__global__ __launch_bounds__(256) void dinv_kernel(const int* __restrict__ counts,
                                                   const int* __restrict__ nt,
                                                   float* __restrict__ dinv,
                                                   float* __restrict__ mcnt, int N) {
  int i = blockIdx.x * blockDim.x + threadIdx.x;
  int stride = gridDim.x * blockDim.x;
  for (int j = i; j < N; j += stride) {
    dinv[j] = rsqrtf(1.0f + (float)counts[j]);
    unsigned long long b = __ballot(nt[j] == 0);
    if ((threadIdx.x & 63) == 0) atomicAdd(mcnt, (float)__popcll(b));
  }
}

// ---------------- exclusive scan -> rowstart, fill ----------------
__global__ __launch_bounds__(1024) void scan_kernel(const int* __restrict__ counts,
                                                    int* __restrict__ rowstart,
                                                    int* __restrict__ fill, int N) {
  __shared__ int sdata[1024];
  __shared__ int running;
  if (threadIdx.x == 0) running = 0;
  __syncthreads();
  int nch = (N + 1023) / 1024;
  for (int ch = 0; ch < nch; ++ch) {
    int base = running;
    int i = ch * 1024 + threadIdx.x;
    int v = (i < N) ? counts[i] : 0;
    sdata[threadIdx.x] = v;
    __syncthreads();
#pragma unroll
    for (int off = 1; off < 1024; off <<= 1) {
      int t = (threadIdx.x >= off) ? sdata[threadIdx.x - off] : 0;
      __syncthreads();
      sdata[threadIdx.x] += t;
      __syncthreads();
    }
    int excl = sdata[threadIdx.x] - v;
    if (i < N) {
      rowstart[i] = base + excl;
      fill[i] = base + excl;
    }
    int tot = sdata[1023];
    __syncthreads();
    if (threadIdx.x == 0) running = base + tot;
    __syncthreads();
  }
  if (threadIdx.x == 0) rowstart[N] = running;
}

// ---------------- bucket active edges by dst ----------------
__global__ __launch_bounds__(256) void fill_kernel(const int* __restrict__ ei,
                                                   const int* __restrict__ nt,
                                                   const float* __restrict__ dinv,
                                                   int* __restrict__ fill,
                                                   int* __restrict__ csr_src,
                                                   float* __restrict__ csr_w, int E) {
  int i = blockIdx.x * blockDim.x + threadIdx.x;
  int stride = gridDim.x * blockDim.x;
  for (int e = i; e < E; e += stride) {
    int s = ei[e], d = ei[E + e];
    if (nt[s] == 0 && nt[d] == 0) {
      int pos = atomicAdd(&fill[d], 1);
      csr_src[pos] = s;
      csr_w[pos] = dinv[s] * dinv[d];
    }
  }
}

// ---------------- pre-split + transpose weights: WT[hi/lo][FOUT][FIN] ----------
__global__ __launch_bounds__(256) void wsplit_kernel(const float* __restrict__ W,
                                                     u16* __restrict__ Th,
                                                     u16* __restrict__ Tl,
                                                     int FIN, int FOUT) {
  int i = blockIdx.x * blockDim.x + threadIdx.x;
  if (i >= FIN * FOUT) return;
  int k = i / FOUT, c = i % FOUT;
  u16 h, l;
  split2(W[i], h, l);
  Th[(size_t)c * FIN + k] = h;
  Tl[(size_t)c * FIN + k] = l;
}

// ---------------- z = emb[x], split to bf16 hi/lo ----------------
__global__ __launch_bounds__(256) void embed_split_kernel(const int* __restrict__ x,
                                                          const float* __restrict__ emb,
                                                          u16* __restrict__ Ah,
                                                          u16* __restrict__ Al, int N) {
  int i = blockIdx.x * blockDim.x + threadIdx.x;
  int stride = gridDim.x * blockDim.x;
  int total = N * (HDIM / 4);
  for (int j = i; j < total; j += stride) {
    int row = j >> 4;
    int c = (j & 15) * 4;
    int xr = x[row];
    float4 v = *(const float4*)&emb[(size_t)xr * HDIM + c];
    u16 h0, l0, h1, l1, h2, l2, h3, l3;
    split2(v.x, h0, l0); split2(v.y, h1, l1);
    split2(v.z, h2, l2); split2(v.w, h3, l3);
    uint2v hp = {(unsigned)h0 | ((unsigned)h1 << 16), (unsigned)h2 | ((unsigned)h3 << 16)};
    uint2v lp = {(unsigned)l0 | ((unsigned)l1 << 16), (unsigned)l2 | ((unsigned)l3 << 16)};
    *(uint2v*)&Ah[(size_t)row * HDIM + c] = hp;
    *(uint2v*)&Al[(size_t)row * HDIM + c] = lp;
  }
}

// ------- split-bf16 MFMA GEMM: Out[N,FOUT] = A[N,FIN] @ W[FIN,FOUT] (fp32 acc) ----
// A given as bf16 hi/lo [N][FIN]; W given pre-split TRANSPOSED [FOUT][FIN].
// Tile 128x64, 256 threads (4 waves), wave = 32 rows x 64 cols, K-chunk 64.
// LDS layout: 16B slot s = gp*ROWS + r holds k-groups (gp,h=0) and (gp,h=1):
// for element k: g=k/4, h=(g>>2)&1, gp=(g&3)|((g>>3)<<2) -> one ds_read_b128/frag.
template <int FIN, int FOUT>
__global__ __launch_bounds__(256) void gemm_split_kernel(const u16* __restrict__ Ah,
                                                         const u16* __restrict__ Al,
                                                         const u16* __restrict__ Wh,
                                                         const u16* __restrict__ Wl,
                                                         float* __restrict__ Out, int N) {
  __shared__ u16 AH[8 * 128 * 8], AL[8 * 128 * 8];
  __shared__ u16 WH[8 * 64 * 8], WL[8 * 64 * 8];
  const int tid = threadIdx.x;
  const int lane = tid & 63, w = tid >> 6;
  const int l15 = lane & 15, l4 = lane >> 4;
  const int r0 = blockIdx.x * 128, c0 = blockIdx.y * 64;
  f32x4 acc[2][4] = {};

  for (int k0 = 0; k0 < FIN; k0 += 64) {
    // ---- stage A hi/lo: 128 rows x 64 k ----
#pragma unroll
    for (int p = 0; p < 4; ++p) {
      int e = p * 2048 + tid * 8;
      int r = e >> 6, ke = e & 63;
      int g0 = ke >> 2;                       // even
      int h = (g0 >> 2) & 1;
      int gp = (g0 & 3) | ((g0 >> 3) << 2);
      uint2v vh0 = {0, 0}, vh1 = {0, 0}, vl0 = {0, 0}, vl1 = {0, 0};
      if (r0 + r < N) {
        size_t gbase = (size_t)(r0 + r) * FIN + k0 + ke;
        vh0 = *(const uint2v*)&Ah[gbase];
        vh1 = *(const uint2v*)&Ah[gbase + 4];
        vl0 = *(const uint2v*)&Al[gbase];
        vl1 = *(const uint2v*)&Al[gbase + 4];
      }
      *(uint2v*)&AH[((gp * 128 + r) * 8) + h * 4] = vh0;
      *(uint2v*)&AH[(((gp + 1) * 128 + r) * 8) + h * 4] = vh1;
      *(uint2v*)&AL[((gp * 128 + r) * 8) + h * 4] = vl0;
      *(uint2v*)&AL[(((gp + 1) * 128 + r) * 8) + h * 4] = vl1;
    }
    // ---- stage W hi/lo: 64 cols x 64 k (WT is [FOUT][FIN]) ----
#pragma unroll
    for (int p = 0; p < 2; ++p) {
      int e = p * 2048 + tid * 8;
      int c = e >> 6, ke = e & 63;
      int g0 = ke >> 2;
      int h = (g0 >> 2) & 1;
      int gp = (g0 & 3) | ((g0 >> 3) << 2);
      size_t gbase = (size_t)(c0 + c) * FIN + k0 + ke;
      uint2v vh0 = *(const uint2v*)&Wh[gbase];
      uint2v vh1 = *(const uint2v*)&Wh[gbase + 4];
      uint2v vl0 = *(const uint2v*)&Wl[gbase];
      uint2v vl1 = *(const uint2v*)&Wl[gbase + 4];
      *(uint2v*)&WH[((gp * 64 + c) * 8) + h * 4] = vh0;
      *(uint2v*)&WH[(((gp + 1) * 64 + c) * 8) + h * 4] = vh1;
      *(uint2v*)&WL[((gp * 64 + c) * 8) + h * 4] = vl0;
      *(uint2v*)&WL[(((gp + 1) * 64 + c) * 8) + h * 4] = vl1;
    }
    __syncthreads();
    // ---- compute: 2 MFMA K-steps of 32 ----
#pragma unroll
    for (int ko = 0; ko < 2; ++ko) {
      const int gb = ko * 4 + l4;
      short8 ah[2], al[2], wh[4], wl[4];
#pragma unroll
      for (int mi = 0; mi < 2; ++mi) {
        int slot = gb * 128 + (w * 32 + mi * 16 + l15);
        ah[mi] = *(const short8*)&AH[slot * 8];
        al[mi] = *(const short8*)&AL[slot * 8];
      }
#pragma unroll
      for (int ni = 0; ni < 4; ++ni) {
        int slot = gb * 64 + (ni * 16 + l15);
        wh[ni] = *(const short8*)&WH[slot * 8];
        wl[ni] = *(const short8*)&WL[slot * 8];
      }
#pragma unroll
      for (int mi = 0; mi < 2; ++mi)
#pragma unroll
        for (int ni = 0; ni < 4; ++ni) {
          acc[mi][ni] = __builtin_amdgcn_mfma_f32_16x16x32_bf16(ah[mi], wh[ni], acc[mi][ni], 0, 0, 0);
          acc[mi][ni] = __builtin_amdgcn_mfma_f32_16x16x32_bf16(ah[mi], wl[ni], acc[mi][ni], 0, 0, 0);
          acc[mi][ni] = __builtin_amdgcn_mfma_f32_16x16x32_bf16(al[mi], wh[ni], acc[mi][ni], 0, 0, 0);
        }
    }
    __syncthreads();
  }
  // ---- epilogue: C/D layout col=lane&15, row=4*(lane>>4)+reg ----
#pragma unroll
  for (int mi = 0; mi < 2; ++mi)
#pragma unroll
    for (int ni = 0; ni < 4; ++ni)
#pragma unroll
      for (int j = 0; j < 4; ++j) {
        int row = r0 + w * 32 + mi * 16 + l4 * 4 + j;
        if (row < N) Out[(size_t)row * FOUT + c0 + ni * 16 + l15] = acc[mi][ni][j];
      }
}

// ---- pull aggregation, fused relu + bf16-split output (layers 1,2) ----
template <int FOUT>
__global__ __launch_bounds__(256) void aggregate_split_kernel(
    const float* __restrict__ HW, const int* __restrict__ rowstart,
    const int* __restrict__ csr_src, const float* __restrict__ csr_w,
    const float* __restrict__ dinv, const float* __restrict__ bias,
    u16* __restrict__ Ah, u16* __restrict__ Al, int N) {
  const int lane = threadIdx.x & 63;
  const int wid = (int)((blockIdx.x * blockDim.x + threadIdx.x) >> 6);
  const int nw = (int)((gridDim.x * blockDim.x) >> 6);
  const bool act = (4 * lane) < FOUT;
  for (int r = wid; r < N; r += nw) {
    const int e0 = rowstart[r];
    const int e1 = rowstart[r + 1];
    float4 acc = {0.f, 0.f, 0.f, 0.f};
    if (act) {
      float di = dinv[r];
      float sn = di * di;
      float4 v = *(const float4*)&HW[(size_t)r * FOUT + 4 * lane];
      float4 bb = *(const float4*)&bias[4 * lane];
      acc.x = sn * v.x + bb.x; acc.y = sn * v.y + bb.y;
      acc.z = sn * v.z + bb.z; acc.w = sn * v.w + bb.w;
    }
    for (int e = e0; e < e1; ++e) {
      int s = csr_src[e];
      float w = csr_w[e];
      if (act) {
        float4 v = *(const float4*)&HW[(size_t)s * FOUT + 4 * lane];
        acc.x += w * v.x; acc.y += w * v.y;
        acc.z += w * v.z; acc.w += w * v.w;
      }
    }
    if (act) {
      acc.x = fmaxf(acc.x, 0.f); acc.y = fmaxf(acc.y, 0.f);
      acc.z = fmaxf(acc.z, 0.f); acc.w = fmaxf(acc.w, 0.f);
      u16 h0, l0, h1, l1, h2, l2, h3, l3;
      split2(acc.x, h0, l0); split2(acc.y, h1, l1);
      split2(acc.z, h2, l2); split2(acc.w, h3, l3);
      uint2v hp = {(unsigned)h0 | ((unsigned)h1 << 16), (unsigned)h2 | ((unsigned)h3 << 16)};
      uint2v lp = {(unsigned)l0 | ((unsigned)l1 << 16), (unsigned)l2 | ((unsigned)l3 << 16)};
      *(uint2v*)&Ah[(size_t)r * FOUT + 4 * lane] = hp;
      *(uint2v*)&Al[(size_t)r * FOUT + 4 * lane] = lp;
    }
  }
}

// ---- layer-3 aggregation fused with masked mean-pool partials (z3 never stored) --
__global__ __launch_bounds__(256) void agg3_pool_kernel(
    const float* __restrict__ HW, const int* __restrict__ rowstart,
    const int* __restrict__ csr_src, const float* __restrict__ csr_w,
    const float* __restrict__ dinv, const float* __restrict__ bias,
    const int* __restrict__ nt, float* __restrict__ pooled, int N) {
  __shared__ float pacc[F3];
  for (int i = threadIdx.x; i < F3; i += 256) pacc[i] = 0.0f;
  __syncthreads();
  const int lane = threadIdx.x & 63;
  const int wid = (int)((blockIdx.x * blockDim.x + threadIdx.x) >> 6);
  const int nw = (int)((gridDim.x * blockDim.x) >> 6);
  const bool act = (4 * lane) < F3;
  for (int r = wid; r < N; r += nw) {
    if (nt[r] != 0) continue;  // only masked nodes contribute to pooled
    const int e0 = rowstart[r];
    const int e1 = rowstart[r + 1];
    float4 acc = {0.f, 0.f, 0.f, 0.f};
    if (act) {
      float di = dinv[r];
      float sn = di * di;
      float4 v = *(const float4*)&HW[(size_t)r * F3 + 4 * lane];
      float4 bb = *(const float4*)&bias[4 * lane];
      acc.x = sn * v.x + bb.x; acc.y = sn * v.y + bb.y;
      acc.z = sn * v.z + bb.z; acc.w = sn * v.w + bb.w;
    }
    for (int e = e0; e < e1; ++e) {
      int s = csr_src[e];
      float w = csr_w[e];
      if (act) {
        float4 v = *(const float4*)&HW[(size_t)s * F3 + 4 * lane];
        acc.x += w * v.x; acc.y += w * v.y;
        acc.z += w * v.z; acc.w += w * v.w;
      }
    }
    if (act) {
      atomicAdd(&pacc[4 * lane + 0], fmaxf(acc.x, 0.f));
      atomicAdd(&pacc[4 * lane + 1], fmaxf(acc.y, 0.f));
      atomicAdd(&pacc[4 * lane + 2], fmaxf(acc.z, 0.f));
      atomicAdd(&pacc[4 * lane + 3], fmaxf(acc.w, 0.f));
    }
  }
  __syncthreads();
  for (int i = threadIdx.x; i < F3; i += 256) atomicAdd(&pooled[i], pacc[i]);
}

// ---------------- phead = bh1 + (pooled/mcnt) @ Wh1[0:192,:] ----------------
__global__ __launch_bounds__(128) void phead_kernel(const float* __restrict__ pooled,
                                                    const float* __restrict__ mcnt,
                                                    const float* __restrict__ Wh1,
                                                    const float* __restrict__ bh1,
                                                    float* __restrict__ phead) {
  int t = threadIdx.x;
  float inv = 1.0f / *mcnt;
  float acc = bh1[t];
  for (int k = 0; k < F3; ++k) acc += pooled[k] * inv * Wh1[k * FH + t];
  phead[t] = acc;
}

// ---------------- head ----------------
__global__ __launch_bounds__(256) void head_kernel(const int* __restrict__ x,
                                                   const float* __restrict__ emb,
                                                   const float* __restrict__ Wh1,
                                                   const float* __restrict__ phead,
                                                   const float* __restrict__ gamma,
                                                   const float* __restrict__ beta,
                                                   const float* __restrict__ Wh2,
                                                   const float* __restrict__ bh2,
                                                   float* __restrict__ out, int N) {
  const int lane = threadIdx.x & 63;
  const int wid = (int)((blockIdx.x * blockDim.x + threadIdx.x) >> 6);
  const int nw = (int)((gridDim.x * blockDim.x) >> 6);
  const float bninv = 1.0f / sqrtf(1.0f + 1e-5f);
  const float ph0 = phead[lane], ph1 = phead[64 + lane];
  const float ga0 = gamma[lane] * bninv, ga1 = gamma[64 + lane] * bninv;
  const float be0 = beta[lane], be1 = beta[64 + lane];
  const float w20 = Wh2[lane], w21 = Wh2[64 + lane];
  const float bias2 = bh2[0];
  for (int r = wid; r < N; r += nw) {
    int xr = x[r];
    float ev = emb[(size_t)xr * HDIM + lane];
    float a0 = 0.f, a1 = 0.f;
#pragma unroll
    for (int k = 0; k < HDIM; ++k) {
      float zk = __shfl(ev, k);
      a0 += zk * Wh1[(size_t)(F3 + k) * FH + lane];
      a1 += zk * Wh1[(size_t)(F3 + k) * FH + 64 + lane];
    }
    float h0 = fmaxf(ph0 + a0, 0.f) * ga0 + be0;
    float h1 = fmaxf(ph1 + a1, 0.f) * ga1 + be1;
    float contrib = h0 * w20 + h1 * w21;
#pragma unroll
    for (int off = 32; off; off >>= 1) contrib += __shfl_xor(contrib, off);
    if (lane == 0) out[r] = contrib + bias2;
  }
}

extern "C" void kernel_launch(void* const* d_in, const int* in_sizes, int n_in,
                              void* d_out, int out_size, void* d_ws, size_t ws_size,
                              hipStream_t stream) {
  const int N = in_sizes[0];
  const int E = in_sizes[1] / 2;

  const int* x = (const int*)d_in[0];
  const int* ei = (const int*)d_in[1];
  const int* nt = (const int*)d_in[2];
  const float* emb = (const float*)d_in[3];
  const float* W1 = (const float*)d_in[4];
  const float* b1 = (const float*)d_in[5];
  const float* W2 = (const float*)d_in[6];
  const float* b2 = (const float*)d_in[7];
  const float* W3 = (const float*)d_in[8];
  const float* b3 = (const float*)d_in[9];
  const float* Wh1 = (const float*)d_in[10];
  const float* bh1 = (const float*)d_in[11];
  const float* gamma = (const float*)d_in[12];
  const float* beta = (const float*)d_in[13];
  const float* Wh2 = (const float*)d_in[14];
  const float* bh2 = (const float*)d_in[15];
  float* out = (float*)d_out;

  // workspace layout
  float* ws = (float*)d_ws;
  float* B = ws;                                   // N*256 fp32 (hw)
  u16* Ahi = (u16*)(B + (size_t)N * 256);          // N*256 bf16-hi
  u16* Alo = Ahi + (size_t)N * 256;                // N*256 bf16-lo
  u16* WTh = Alo + (size_t)N * 256;                // 131072 (W1T|W2T|W3T)
  u16* WTl = WTh + 131072;                         // 131072
  float* dinv = (float*)(WTl + 131072);            // N
  float* csr_w = dinv + N;                         // E
  int* csr_src = (int*)(csr_w + E);                // E
  int* counts = csr_src + E;                       // N
  int* fill = counts + N;                          // N
  int* rowstart = fill + N;                        // N+1
  float* pooled = (float*)(rowstart + N + 1);      // 192
  float* phead = pooled + F3;                      // 128
  float* mcnt = phead + FH;                        // 1
  (void)ws_size; (void)n_in; (void)out_size;

  u16* W1Th = WTh,       * W1Tl = WTl;             // [256][64]
  u16* W2Th = WTh + 16384, * W2Tl = WTl + 16384;   // [256][256]
  u16* W3Th = WTh + 81920, * W3Tl = WTl + 81920;   // [192][256]

  const int rowBlocks = (N + 127) / 128;
  const int aggBlocks = (N + 3) / 4;

  init_kernel<<<256, 256, 0, stream>>>(counts, pooled, mcnt, N);
  count_kernel<<<1024, 256, 0, stream>>>(ei, nt, counts, E);
  dinv_kernel<<<256, 256, 0, stream>>>(counts, nt, dinv, mcnt, N);
  scan_kernel<<<1, 1024, 0, stream>>>(counts, rowstart, fill, N);
  fill_kernel<<<1024, 256, 0, stream>>>(ei, nt, dinv, fill, csr_src, csr_w, E);
  wsplit_kernel<<<(HDIM * F1 + 255) / 256, 256, 0, stream>>>(W1, W1Th, W1Tl, HDIM, F1);
  wsplit_kernel<<<(F1 * F1 + 255) / 256, 256, 0, stream>>>(W2, W2Th, W2Tl, F1, F1);
  wsplit_kernel<<<(F1 * F3 + 255) / 256, 256, 0, stream>>>(W3, W3Th, W3Tl, F1, F3);
  embed_split_kernel<<<2048, 256, 0, stream>>>(x, emb, Ahi, Alo, N);

  // layer 1
  gemm_split_kernel<HDIM, F1><<<dim3(rowBlocks, F1 / 64), 256, 0, stream>>>(Ahi, Alo, W1Th, W1Tl, B, N);
  aggregate_split_kernel<F1><<<aggBlocks, 256, 0, stream>>>(B, rowstart, csr_src, csr_w, dinv, b1, Ahi, Alo, N);

  // layer 2
  gemm_split_kernel<F1, F1><<<dim3(rowBlocks, F1 / 64), 256, 0, stream>>>(Ahi, Alo, W2Th, W2Tl, B, N);
  aggregate_split_kernel<F1><<<aggBlocks, 256, 0, stream>>>(B, rowstart, csr_src, csr_w, dinv, b2, Ahi, Alo, N);

  // layer 3 (+ fused masked pool; z3 never materialized)
  gemm_split_kernel<F1, F3><<<dim3(rowBlocks, F3 / 64), 256, 0, stream>>>(Ahi, Alo, W3Th, W3Tl, B, N);
  agg3_pool_kernel<<<2048, 256, 0, stream>>>(B, rowstart, csr_src, csr_w, dinv, b3, nt, pooled, N);

  // head
  phead_kernel<<<1, 128, 0, stream>>>(pooled, mcnt, Wh1, bh1, phead);
  head_kernel<<<768, 256, 0, stream>>>(x, emb, Wh1, phead, gamma, beta, Wh2, bh2, out, N);
}

// Round 4
// 424.219 us; speedup vs baseline: 6.7760x; 1.2023x over previous
//
#include <hip/hip_runtime.h>

#define HDIM 64
#define F1 256
#define F3 192
#define FH 128

typedef unsigned short u16;
typedef __attribute__((ext_vector_type(8))) short short8;
typedef __attribute__((ext_vector_type(4))) float f32x4;
typedef __attribute__((ext_vector_type(2))) unsigned int uint2v;

// fp32 -> bf16(hi) + bf16(lo), both RNE
__device__ __forceinline__ void split2(float v, u16& h, u16& l) {
  unsigned u = __float_as_uint(v);
  unsigned r = u + 0x7FFFu + ((u >> 16) & 1u);
  h = (u16)(r >> 16);
  float fh = __uint_as_float(((unsigned)h) << 16);
  float res = v - fh;
  unsigned u2 = __float_as_uint(res);
  unsigned r2 = u2 + 0x7FFFu + ((u2 >> 16) & 1u);
  l = (u16)(r2 >> 16);
}

// ---------------- init ----------------
__global__ __launch_bounds__(256) void init_kernel(int* counts, float* pooled,
                                                   float* mcnt, int N) {
  int i = blockIdx.x * blockDim.x + threadIdx.x;
  int stride = gridDim.x * blockDim.x;
  for (int j = i; j < N; j += stride) counts[j] = 0;
  if (i < F3) pooled[i] = 0.0f;
  if (i == 0) *mcnt = 0.0f;
}

// ---------------- masked in-degree ----------------
__global__ __launch_bounds__(256) void count_kernel(const int* __restrict__ ei,
                                                    const int* __restrict__ nt,
                                                    int* __restrict__ counts, int E) {
  int i = blockIdx.x * blockDim.x + threadIdx.x;
  int stride = gridDim.x * blockDim.x;
  for (int e = i; e < E; e += stride) {
    int s = ei[e], d = ei[E + e];
    if (nt[s] == 0 && nt[d] == 0) atomicAdd(&counts[d], 1);
  }
}

// ---------------- counts -> dinv, masked count ----------------
__global__ __launch_bounds__(256) void dinv_kernel(const int* __restrict__ counts,
                                                   const int* __restrict__ nt,
                                                   float* __restrict__ dinv,
                                                   float* __restrict__ mcnt, int N) {
  int i = blockIdx.x * blockDim.x + threadIdx.x;
  int stride = gridDim.x * blockDim.x;
  for (int j = i; j < N; j += stride) {
    dinv[j] = rsqrtf(1.0f + (float)counts[j]);
    unsigned long long b = __ballot(nt[j] == 0);
    if ((threadIdx.x & 63) == 0) atomicAdd(mcnt, (float)__popcll(b));
  }
}

// ---------------- multi-block exclusive scan (3 phases) ----------------
// phase 1: per-block (1024 elems) sums
__global__ __launch_bounds__(256) void scan_phase1(const int* __restrict__ counts,
                                                   int* __restrict__ blocksum, int N) {
  __shared__ int wsum[4];
  int base = blockIdx.x * 1024 + threadIdx.x * 4;
  int s = 0;
#pragma unroll
  for (int j = 0; j < 4; ++j) {
    int i = base + j;
    if (i < N) s += counts[i];
  }
#pragma unroll
  for (int off = 32; off; off >>= 1) s += __shfl_xor(s, off);
  if ((threadIdx.x & 63) == 0) wsum[threadIdx.x >> 6] = s;
  __syncthreads();
  if (threadIdx.x == 0)
    blocksum[blockIdx.x] = wsum[0] + wsum[1] + wsum[2] + wsum[3];
}

// phase 2: one wave scans block sums in-place -> exclusive block offsets
__global__ __launch_bounds__(64) void scan_phase2(int* __restrict__ blocksum, int G) {
  int tid = threadIdx.x;
  int run = 0;
  for (int b0 = 0; b0 < G; b0 += 64) {
    int i = b0 + tid;
    int orig = (i < G) ? blocksum[i] : 0;
    int v = orig;
#pragma unroll
    for (int off = 1; off < 64; off <<= 1) {
      int t = __shfl_up(v, off);
      if (tid >= off) v += t;
    }
    if (i < G) blocksum[i] = run + v - orig;  // exclusive
    run += __shfl(v, 63);
  }
}

// phase 3: local exclusive scan + block offset -> rowstart, fill
__global__ __launch_bounds__(256) void scan_phase3(const int* __restrict__ counts,
                                                   const int* __restrict__ blocksum,
                                                   int* __restrict__ rowstart,
                                                   int* __restrict__ fill, int N) {
  __shared__ int wsum[4];
  const int tid = threadIdx.x;
  int base = blockIdx.x * 1024 + tid * 4;
  int c[4];
  int tsum = 0;
#pragma unroll
  for (int j = 0; j < 4; ++j) {
    int i = base + j;
    c[j] = (i < N) ? counts[i] : 0;
    tsum += c[j];
  }
  int v = tsum;
#pragma unroll
  for (int off = 1; off < 64; off <<= 1) {
    int t = __shfl_up(v, off);
    if ((tid & 63) >= off) v += t;
  }
  int wexcl = v - tsum;
  if ((tid & 63) == 63) wsum[tid >> 6] = v;
  __syncthreads();
  int wbase = 0;
  int wv = tid >> 6;
#pragma unroll
  for (int j = 0; j < 4; ++j)
    if (j < wv) wbase += wsum[j];
  int off0 = blocksum[blockIdx.x] + wbase + wexcl;
#pragma unroll
  for (int j = 0; j < 4; ++j) {
    int i = base + j;
    if (i < N) {
      rowstart[i] = off0;
      fill[i] = off0;
      off0 += c[j];
      if (i == N - 1) rowstart[N] = off0;
    }
  }
}

// ---------------- bucket active edges by dst ----------------
__global__ __launch_bounds__(256) void fill_kernel(const int* __restrict__ ei,
                                                   const int* __restrict__ nt,
                                                   const float* __restrict__ dinv,
                                                   int* __restrict__ fill,
                                                   int* __restrict__ csr_src,
                                                   float* __restrict__ csr_w, int E) {
  int i = blockIdx.x * blockDim.x + threadIdx.x;
  int stride = gridDim.x * blockDim.x;
  for (int e = i; e < E; e += stride) {
    int s = ei[e], d = ei[E + e];
    if (nt[s] == 0 && nt[d] == 0) {
      int pos = atomicAdd(&fill[d], 1);
      csr_src[pos] = s;
      csr_w[pos] = dinv[s] * dinv[d];
    }
  }
}

// ---------------- pre-split + transpose weights: WT[hi/lo][FOUT][FIN] ----------
__global__ __launch_bounds__(256) void wsplit_kernel(const float* __restrict__ W,
                                                     u16* __restrict__ Th,
                                                     u16* __restrict__ Tl,
                                                     int FIN, int FOUT) {
  int i = blockIdx.x * blockDim.x + threadIdx.x;
  if (i >= FIN * FOUT) return;
  int k = i / FOUT, c = i % FOUT;
  u16 h, l;
  split2(W[i], h, l);
  Th[(size_t)c * FIN + k] = h;
  Tl[(size_t)c * FIN + k] = l;
}

// ---------------- z = emb[x], split to bf16 hi/lo ----------------
__global__ __launch_bounds__(256) void embed_split_kernel(const int* __restrict__ x,
                                                          const float* __restrict__ emb,
                                                          u16* __restrict__ Ah,
                                                          u16* __restrict__ Al, int N) {
  int i = blockIdx.x * blockDim.x + threadIdx.x;
  int stride = gridDim.x * blockDim.x;
  int total = N * (HDIM / 4);
  for (int j = i; j < total; j += stride) {
    int row = j >> 4;
    int c = (j & 15) * 4;
    int xr = x[row];
    float4 v = *(const float4*)&emb[(size_t)xr * HDIM + c];
    u16 h0, l0, h1, l1, h2, l2, h3, l3;
    split2(v.x, h0, l0); split2(v.y, h1, l1);
    split2(v.z, h2, l2); split2(v.w, h3, l3);
    uint2v hp = {(unsigned)h0 | ((unsigned)h1 << 16), (unsigned)h2 | ((unsigned)h3 << 16)};
    uint2v lp = {(unsigned)l0 | ((unsigned)l1 << 16), (unsigned)l2 | ((unsigned)l3 << 16)};
    *(uint2v*)&Ah[(size_t)row * HDIM + c] = hp;
    *(uint2v*)&Al[(size_t)row * HDIM + c] = lp;
  }
}

// ------- split-bf16 MFMA GEMM: Out[N,FOUT] = A[N,FIN] @ W[FIN,FOUT] (fp32 acc) ----
template <int FIN, int FOUT>
__global__ __launch_bounds__(256) void gemm_split_kernel(const u16* __restrict__ Ah,
                                                         const u16* __restrict__ Al,
                                                         const u16* __restrict__ Wh,
                                                         const u16* __restrict__ Wl,
                                                         float* __restrict__ Out, int N) {
  __shared__ u16 AH[8 * 128 * 8], AL[8 * 128 * 8];
  __shared__ u16 WH[8 * 64 * 8], WL[8 * 64 * 8];
  const int tid = threadIdx.x;
  const int lane = tid & 63, w = tid >> 6;
  const int l15 = lane & 15, l4 = lane >> 4;
  const int r0 = blockIdx.x * 128, c0 = blockIdx.y * 64;
  f32x4 acc[2][4] = {};

  for (int k0 = 0; k0 < FIN; k0 += 64) {
#pragma unroll
    for (int p = 0; p < 4; ++p) {
      int e = p * 2048 + tid * 8;
      int r = e >> 6, ke = e & 63;
      int g0 = ke >> 2;
      int h = (g0 >> 2) & 1;
      int gp = (g0 & 3) | ((g0 >> 3) << 2);
      uint2v vh0 = {0, 0}, vh1 = {0, 0}, vl0 = {0, 0}, vl1 = {0, 0};
      if (r0 + r < N) {
        size_t gbase = (size_t)(r0 + r) * FIN + k0 + ke;
        vh0 = *(const uint2v*)&Ah[gbase];
        vh1 = *(const uint2v*)&Ah[gbase + 4];
        vl0 = *(const uint2v*)&Al[gbase];
        vl1 = *(const uint2v*)&Al[gbase + 4];
      }
      *(uint2v*)&AH[((gp * 128 + r) * 8) + h * 4] = vh0;
      *(uint2v*)&AH[(((gp + 1) * 128 + r) * 8) + h * 4] = vh1;
      *(uint2v*)&AL[((gp * 128 + r) * 8) + h * 4] = vl0;
      *(uint2v*)&AL[(((gp + 1) * 128 + r) * 8) + h * 4] = vl1;
    }
#pragma unroll
    for (int p = 0; p < 2; ++p) {
      int e = p * 2048 + tid * 8;
      int c = e >> 6, ke = e & 63;
      int g0 = ke >> 2;
      int h = (g0 >> 2) & 1;
      int gp = (g0 & 3) | ((g0 >> 3) << 2);
      size_t gbase = (size_t)(c0 + c) * FIN + k0 + ke;
      uint2v vh0 = *(const uint2v*)&Wh[gbase];
      uint2v vh1 = *(const uint2v*)&Wh[gbase + 4];
      uint2v vl0 = *(const uint2v*)&Wl[gbase];
      uint2v vl1 = *(const uint2v*)&Wl[gbase + 4];
      *(uint2v*)&WH[((gp * 64 + c) * 8) + h * 4] = vh0;
      *(uint2v*)&WH[(((gp + 1) * 64 + c) * 8) + h * 4] = vh1;
      *(uint2v*)&WL[((gp * 64 + c) * 8) + h * 4] = vl0;
      *(uint2v*)&WL[(((gp + 1) * 64 + c) * 8) + h * 4] = vl1;
    }
    __syncthreads();
#pragma unroll
    for (int ko = 0; ko < 2; ++ko) {
      const int gb = ko * 4 + l4;
      short8 ah[2], al[2], wh[4], wl[4];
#pragma unroll
      for (int mi = 0; mi < 2; ++mi) {
        int slot = gb * 128 + (w * 32 + mi * 16 + l15);
        ah[mi] = *(const short8*)&AH[slot * 8];
        al[mi] = *(const short8*)&AL[slot * 8];
      }
#pragma unroll
      for (int ni = 0; ni < 4; ++ni) {
        int slot = gb * 64 + (ni * 16 + l15);
        wh[ni] = *(const short8*)&WH[slot * 8];
        wl[ni] = *(const short8*)&WL[slot * 8];
      }
#pragma unroll
      for (int mi = 0; mi < 2; ++mi)
#pragma unroll
        for (int ni = 0; ni < 4; ++ni) {
          acc[mi][ni] = __builtin_amdgcn_mfma_f32_16x16x32_bf16(ah[mi], wh[ni], acc[mi][ni], 0, 0, 0);
          acc[mi][ni] = __builtin_amdgcn_mfma_f32_16x16x32_bf16(ah[mi], wl[ni], acc[mi][ni], 0, 0, 0);
          acc[mi][ni] = __builtin_amdgcn_mfma_f32_16x16x32_bf16(al[mi], wh[ni], acc[mi][ni], 0, 0, 0);
        }
    }
    __syncthreads();
  }
#pragma unroll
  for (int mi = 0; mi < 2; ++mi)
#pragma unroll
    for (int ni = 0; ni < 4; ++ni)
#pragma unroll
      for (int j = 0; j < 4; ++j) {
        int row = r0 + w * 32 + mi * 16 + l4 * 4 + j;
        if (row < N) Out[(size_t)row * FOUT + c0 + ni * 16 + l15] = acc[mi][ni][j];
      }
}

// ---- pull aggregation, fused relu + bf16-split output (layers 1,2) ----
template <int FOUT>
__global__ __launch_bounds__(256) void aggregate_split_kernel(
    const float* __restrict__ HW, const int* __restrict__ rowstart,
    const int* __restrict__ csr_src, const float* __restrict__ csr_w,
    const float* __restrict__ dinv, const float* __restrict__ bias,
    u16* __restrict__ Ah, u16* __restrict__ Al, int N) {
  const int lane = threadIdx.x & 63;
  const int wid = (int)((blockIdx.x * blockDim.x + threadIdx.x) >> 6);
  const int nw = (int)((gridDim.x * blockDim.x) >> 6);
  const bool act = (4 * lane) < FOUT;
  for (int r = wid; r < N; r += nw) {
    const int e0 = rowstart[r];
    const int e1 = rowstart[r + 1];
    float4 acc = {0.f, 0.f, 0.f, 0.f};
    if (act) {
      float di = dinv[r];
      float sn = di * di;
      float4 v = *(const float4*)&HW[(size_t)r * FOUT + 4 * lane];
      float4 bb = *(const float4*)&bias[4 * lane];
      acc.x = sn * v.x + bb.x; acc.y = sn * v.y + bb.y;
      acc.z = sn * v.z + bb.z; acc.w = sn * v.w + bb.w;
    }
    for (int e = e0; e < e1; ++e) {
      int s = csr_src[e];
      float w = csr_w[e];
      if (act) {
        float4 v = *(const float4*)&HW[(size_t)s * FOUT + 4 * lane];
        acc.x += w * v.x; acc.y += w * v.y;
        acc.z += w * v.z; acc.w += w * v.w;
      }
    }
    if (act) {
      acc.x = fmaxf(acc.x, 0.f); acc.y = fmaxf(acc.y, 0.f);
      acc.z = fmaxf(acc.z, 0.f); acc.w = fmaxf(acc.w, 0.f);
      u16 h0, l0, h1, l1, h2, l2, h3, l3;
      split2(acc.x, h0, l0); split2(acc.y, h1, l1);
      split2(acc.z, h2, l2); split2(acc.w, h3, l3);
      uint2v hp = {(unsigned)h0 | ((unsigned)h1 << 16), (unsigned)h2 | ((unsigned)h3 << 16)};
      uint2v lp = {(unsigned)l0 | ((unsigned)l1 << 16), (unsigned)l2 | ((unsigned)l3 << 16)};
      *(uint2v*)&Ah[(size_t)r * FOUT + 4 * lane] = hp;
      *(uint2v*)&Al[(size_t)r * FOUT + 4 * lane] = lp;
    }
  }
}

// ---- layer-3 aggregation fused with masked mean-pool partials (z3 never stored) --
__global__ __launch_bounds__(256) void agg3_pool_kernel(
    const float* __restrict__ HW, const int* __restrict__ rowstart,
    const int* __restrict__ csr_src, const float* __restrict__ csr_w,
    const float* __restrict__ dinv, const float* __restrict__ bias,
    const int* __restrict__ nt, float* __restrict__ pooled, int N) {
  __shared__ float pacc[F3];
  for (int i = threadIdx.x; i < F3; i += 256) pacc[i] = 0.0f;
  __syncthreads();
  const int lane = threadIdx.x & 63;
  const int wid = (int)((blockIdx.x * blockDim.x + threadIdx.x) >> 6);
  const int nw = (int)((gridDim.x * blockDim.x) >> 6);
  const bool act = (4 * lane) < F3;
  for (int r = wid; r < N; r += nw) {
    if (nt[r] != 0) continue;
    const int e0 = rowstart[r];
    const int e1 = rowstart[r + 1];
    float4 acc = {0.f, 0.f, 0.f, 0.f};
    if (act) {
      float di = dinv[r];
      float sn = di * di;
      float4 v = *(const float4*)&HW[(size_t)r * F3 + 4 * lane];
      float4 bb = *(const float4*)&bias[4 * lane];
      acc.x = sn * v.x + bb.x; acc.y = sn * v.y + bb.y;
      acc.z = sn * v.z + bb.z; acc.w = sn * v.w + bb.w;
    }
    for (int e = e0; e < e1; ++e) {
      int s = csr_src[e];
      float w = csr_w[e];
      if (act) {
        float4 v = *(const float4*)&HW[(size_t)s * F3 + 4 * lane];
        acc.x += w * v.x; acc.y += w * v.y;
        acc.z += w * v.z; acc.w += w * v.w;
      }
    }
    if (act) {
      atomicAdd(&pacc[4 * lane + 0], fmaxf(acc.x, 0.f));
      atomicAdd(&pacc[4 * lane + 1], fmaxf(acc.y, 0.f));
      atomicAdd(&pacc[4 * lane + 2], fmaxf(acc.z, 0.f));
      atomicAdd(&pacc[4 * lane + 3], fmaxf(acc.w, 0.f));
    }
  }
  __syncthreads();
  for (int i = threadIdx.x; i < F3; i += 256) atomicAdd(&pooled[i], pacc[i]);
}

// ---------------- phead = bh1 + (pooled/mcnt) @ Wh1[0:192,:] ----------------
__global__ __launch_bounds__(128) void phead_kernel(const float* __restrict__ pooled,
                                                    const float* __restrict__ mcnt,
                                                    const float* __restrict__ Wh1,
                                                    const float* __restrict__ bh1,
                                                    float* __restrict__ phead) {
  int t = threadIdx.x;
  float inv = 1.0f / *mcnt;
  float acc = bh1[t];
  for (int k = 0; k < F3; ++k) acc += pooled[k] * inv * Wh1[k * FH + t];
  phead[t] = acc;
}

// ---------------- head ----------------
__global__ __launch_bounds__(256) void head_kernel(const int* __restrict__ x,
                                                   const float* __restrict__ emb,
                                                   const float* __restrict__ Wh1,
                                                   const float* __restrict__ phead,
                                                   const float* __restrict__ gamma,
                                                   const float* __restrict__ beta,
                                                   const float* __restrict__ Wh2,
                                                   const float* __restrict__ bh2,
                                                   float* __restrict__ out, int N) {
  const int lane = threadIdx.x & 63;
  const int wid = (int)((blockIdx.x * blockDim.x + threadIdx.x) >> 6);
  const int nw = (int)((gridDim.x * blockDim.x) >> 6);
  const float bninv = 1.0f / sqrtf(1.0f + 1e-5f);
  const float ph0 = phead[lane], ph1 = phead[64 + lane];
  const float ga0 = gamma[lane] * bninv, ga1 = gamma[64 + lane] * bninv;
  const float be0 = beta[lane], be1 = beta[64 + lane];
  const float w20 = Wh2[lane], w21 = Wh2[64 + lane];
  const float bias2 = bh2[0];
  for (int r = wid; r < N; r += nw) {
    int xr = x[r];
    float ev = emb[(size_t)xr * HDIM + lane];
    float a0 = 0.f, a1 = 0.f;
#pragma unroll
    for (int k = 0; k < HDIM; ++k) {
      float zk = __shfl(ev, k);
      a0 += zk * Wh1[(size_t)(F3 + k) * FH + lane];
      a1 += zk * Wh1[(size_t)(F3 + k) * FH + 64 + lane];
    }
    float h0 = fmaxf(ph0 + a0, 0.f) * ga0 + be0;
    float h1 = fmaxf(ph1 + a1, 0.f) * ga1 + be1;
    float contrib = h0 * w20 + h1 * w21;
#pragma unroll
    for (int off = 32; off; off >>= 1) contrib += __shfl_xor(contrib, off);
    if (lane == 0) out[r] = contrib + bias2;
  }
}

extern "C" void kernel_launch(void* const* d_in, const int* in_sizes, int n_in,
                              void* d_out, int out_size, void* d_ws, size_t ws_size,
                              hipStream_t stream) {
  const int N = in_sizes[0];
  const int E = in_sizes[1] / 2;

  const int* x = (const int*)d_in[0];
  const int* ei = (const int*)d_in[1];
  const int* nt = (const int*)d_in[2];
  const float* emb = (const float*)d_in[3];
  const float* W1 = (const float*)d_in[4];
  const float* b1 = (const float*)d_in[5];
  const float* W2 = (const float*)d_in[6];
  const float* b2 = (const float*)d_in[7];
  const float* W3 = (const float*)d_in[8];
  const float* b3 = (const float*)d_in[9];
  const float* Wh1 = (const float*)d_in[10];
  const float* bh1 = (const float*)d_in[11];
  const float* gamma = (const float*)d_in[12];
  const float* beta = (const float*)d_in[13];
  const float* Wh2 = (const float*)d_in[14];
  const float* bh2 = (const float*)d_in[15];
  float* out = (float*)d_out;

  // workspace layout
  float* ws = (float*)d_ws;
  float* B = ws;                                   // N*256 fp32 (hw)
  u16* Ahi = (u16*)(B + (size_t)N * 256);          // N*256 bf16-hi
  u16* Alo = Ahi + (size_t)N * 256;                // N*256 bf16-lo
  u16* WTh = Alo + (size_t)N * 256;                // 131072 (W1T|W2T|W3T)
  u16* WTl = WTh + 131072;                         // 131072
  float* dinv = (float*)(WTl + 131072);            // N
  float* csr_w = dinv + N;                         // E
  int* csr_src = (int*)(csr_w + E);                // E
  int* counts = csr_src + E;                       // N
  int* fill = counts + N;                          // N
  int* rowstart = fill + N;                        // N+1
  int* blocksum = rowstart + N + 2;                // ceil(N/1024)
  float* pooled = (float*)(blocksum + 256);        // 192
  float* phead = pooled + F3;                      // 128
  float* mcnt = phead + FH;                        // 1
  (void)ws_size; (void)n_in; (void)out_size;

  u16* W1Th = WTh,       * W1Tl = WTl;             // [256][64]
  u16* W2Th = WTh + 16384, * W2Tl = WTl + 16384;   // [256][256]
  u16* W3Th = WTh + 81920, * W3Tl = WTl + 81920;   // [192][256]

  const int rowBlocks = (N + 127) / 128;
  const int aggBlocks = (N + 3) / 4;
  const int scanBlocks = (N + 1023) / 1024;

  init_kernel<<<256, 256, 0, stream>>>(counts, pooled, mcnt, N);
  count_kernel<<<1024, 256, 0, stream>>>(ei, nt, counts, E);
  dinv_kernel<<<256, 256, 0, stream>>>(counts, nt, dinv, mcnt, N);
  scan_phase1<<<scanBlocks, 256, 0, stream>>>(counts, blocksum, N);
  scan_phase2<<<1, 64, 0, stream>>>(blocksum, scanBlocks);
  scan_phase3<<<scanBlocks, 256, 0, stream>>>(counts, blocksum, rowstart, fill, N);
  fill_kernel<<<1024, 256, 0, stream>>>(ei, nt, dinv, fill, csr_src, csr_w, E);
  wsplit_kernel<<<(HDIM * F1 + 255) / 256, 256, 0, stream>>>(W1, W1Th, W1Tl, HDIM, F1);
  wsplit_kernel<<<(F1 * F1 + 255) / 256, 256, 0, stream>>>(W2, W2Th, W2Tl, F1, F1);
  wsplit_kernel<<<(F1 * F3 + 255) / 256, 256, 0, stream>>>(W3, W3Th, W3Tl, F1, F3);
  embed_split_kernel<<<2048, 256, 0, stream>>>(x, emb, Ahi, Alo, N);

  // layer 1
  gemm_split_kernel<HDIM, F1><<<dim3(rowBlocks, F1 / 64), 256, 0, stream>>>(Ahi, Alo, W1Th, W1Tl, B, N);
  aggregate_split_kernel<F1><<<aggBlocks, 256, 0, stream>>>(B, rowstart, csr_src, csr_w, dinv, b1, Ahi, Alo, N);

  // layer 2
  gemm_split_kernel<F1, F1><<<dim3(rowBlocks, F1 / 64), 256, 0, stream>>>(Ahi, Alo, W2Th, W2Tl, B, N);
  aggregate_split_kernel<F1><<<aggBlocks, 256, 0, stream>>>(B, rowstart, csr_src, csr_w, dinv, b2, Ahi, Alo, N);

  // layer 3 (+ fused masked pool; z3 never materialized)
  gemm_split_kernel<F1, F3><<<dim3(rowBlocks, F3 / 64), 256, 0, stream>>>(Ahi, Alo, W3Th, W3Tl, B, N);
  agg3_pool_kernel<<<2048, 256, 0, stream>>>(B, rowstart, csr_src, csr_w, dinv, b3, nt, pooled, N);

  // head
  phead_kernel<<<1, 128, 0, stream>>>(pooled, mcnt, Wh1, bh1, phead);
  head_kernel<<<768, 256, 0, stream>>>(x, emb, Wh1, phead, gamma, beta, Wh2, bh2, out, N);
}

// Round 5
// 324.834 us; speedup vs baseline: 8.8491x; 1.3060x over previous
//
#include <hip/hip_runtime.h>

#define HDIM 64
#define F1 256
#define F3 192
#define FH 128

typedef unsigned short u16;
typedef __attribute__((ext_vector_type(8))) short short8;
typedef __attribute__((ext_vector_type(4))) float f32x4;
typedef __attribute__((ext_vector_type(2))) unsigned int uint2v;

// fp32 -> bf16(hi) + bf16(lo), both RNE
__device__ __forceinline__ void split2(float v, u16& h, u16& l) {
  unsigned u = __float_as_uint(v);
  unsigned r = u + 0x7FFFu + ((u >> 16) & 1u);
  h = (u16)(r >> 16);
  float fh = __uint_as_float(((unsigned)h) << 16);
  float res = v - fh;
  unsigned u2 = __float_as_uint(res);
  unsigned r2 = u2 + 0x7FFFu + ((u2 >> 16) & 1u);
  l = (u16)(r2 >> 16);
}

// ---------------- init ----------------
__global__ __launch_bounds__(256) void init_kernel(int* counts, float* pooled, int N) {
  int i = blockIdx.x * blockDim.x + threadIdx.x;
  int stride = gridDim.x * blockDim.x;
  for (int j = i; j < N; j += stride) counts[j] = 0;
  if (i < F3) pooled[i] = 0.0f;
}

// ------------- generic 3-phase exclusive scan, MODE 0: mask(nt==0), 1: counts ----
template <int MODE>
__global__ __launch_bounds__(256) void scan_p1(const int* __restrict__ in,
                                               int* __restrict__ blocksum, int N) {
  __shared__ int wsum[4];
  int base = blockIdx.x * 1024 + threadIdx.x * 4;
  int s = 0;
#pragma unroll
  for (int j = 0; j < 4; ++j) {
    int i = base + j;
    if (i < N) s += (MODE == 0) ? (in[i] == 0 ? 1 : 0) : in[i];
  }
#pragma unroll
  for (int off = 32; off; off >>= 1) s += __shfl_xor(s, off);
  if ((threadIdx.x & 63) == 0) wsum[threadIdx.x >> 6] = s;
  __syncthreads();
  if (threadIdx.x == 0)
    blocksum[blockIdx.x] = wsum[0] + wsum[1] + wsum[2] + wsum[3];
}

__global__ __launch_bounds__(64) void scan_p2(int* __restrict__ blocksum, int G) {
  int tid = threadIdx.x;
  int run = 0;
  for (int b0 = 0; b0 < G; b0 += 64) {
    int i = b0 + tid;
    int orig = (i < G) ? blocksum[i] : 0;
    int v = orig;
#pragma unroll
    for (int off = 1; off < 64; off <<= 1) {
      int t = __shfl_up(v, off);
      if (tid >= off) v += t;
    }
    if (i < G) blocksum[i] = run + v - orig;
    run += __shfl(v, 63);
  }
}

// MODE 0: out0=newidx, out1=nodelist, writes NmInt/mcnt.  MODE 1: out0=rowstart, out1=fill.
template <int MODE>
__global__ __launch_bounds__(256) void scan_p3(const int* __restrict__ in,
                                               const int* __restrict__ blocksum,
                                               int* __restrict__ out0,
                                               int* __restrict__ out1,
                                               int* __restrict__ NmInt,
                                               float* __restrict__ mcnt, int N) {
  __shared__ int wsum[4];
  const int tid = threadIdx.x;
  int base = blockIdx.x * 1024 + tid * 4;
  int c[4];
  int tsum = 0;
#pragma unroll
  for (int j = 0; j < 4; ++j) {
    int i = base + j;
    c[j] = (i < N) ? ((MODE == 0) ? (in[i] == 0 ? 1 : 0) : in[i]) : 0;
    tsum += c[j];
  }
  int v = tsum;
#pragma unroll
  for (int off = 1; off < 64; off <<= 1) {
    int t = __shfl_up(v, off);
    if ((tid & 63) >= off) v += t;
  }
  int wexcl = v - tsum;
  if ((tid & 63) == 63) wsum[tid >> 6] = v;
  __syncthreads();
  int wbase = 0;
  int wv = tid >> 6;
#pragma unroll
  for (int j = 0; j < 4; ++j)
    if (j < wv) wbase += wsum[j];
  int off0 = blocksum[blockIdx.x] + wbase + wexcl;
#pragma unroll
  for (int j = 0; j < 4; ++j) {
    int i = base + j;
    if (i < N) {
      if (MODE == 0) {
        out0[i] = off0;
        if (c[j]) out1[off0] = i;
        off0 += c[j];
        if (i == N - 1) { *NmInt = off0; *mcnt = (float)off0; }
      } else {
        out0[i] = off0;
        out1[i] = off0;
        off0 += c[j];
        if (i == N - 1) out0[N] = off0;
      }
    }
  }
}

// ---------------- masked in-degree in COMPACTED dst space ----------------
__global__ __launch_bounds__(256) void count_kernel(const int* __restrict__ ei,
                                                    const int* __restrict__ nt,
                                                    const int* __restrict__ newidx,
                                                    int* __restrict__ counts, int E) {
  int i = blockIdx.x * blockDim.x + threadIdx.x;
  int stride = gridDim.x * blockDim.x;
  for (int e = i; e < E; e += stride) {
    int s = ei[e], d = ei[E + e];
    if (nt[s] == 0 && nt[d] == 0) atomicAdd(&counts[newidx[d]], 1);
  }
}

// ---------------- counts -> dinv (compacted) ----------------
__global__ __launch_bounds__(256) void dinv_kernel(const int* __restrict__ counts,
                                                   float* __restrict__ dinv,
                                                   const int* __restrict__ NmPtr) {
  int Nm = *NmPtr;
  int i = blockIdx.x * blockDim.x + threadIdx.x;
  int stride = gridDim.x * blockDim.x;
  for (int j = i; j < Nm; j += stride) dinv[j] = rsqrtf(1.0f + (float)counts[j]);
}

// ---------------- bucket active edges by compacted dst ----------------
__global__ __launch_bounds__(256) void fill_kernel(const int* __restrict__ ei,
                                                   const int* __restrict__ nt,
                                                   const int* __restrict__ newidx,
                                                   const float* __restrict__ dinv,
                                                   int* __restrict__ fill,
                                                   int* __restrict__ csr_src,
                                                   float* __restrict__ csr_w, int E) {
  int i = blockIdx.x * blockDim.x + threadIdx.x;
  int stride = gridDim.x * blockDim.x;
  for (int e = i; e < E; e += stride) {
    int s = ei[e], d = ei[E + e];
    if (nt[s] == 0 && nt[d] == 0) {
      int ns = newidx[s], nd = newidx[d];
      int pos = atomicAdd(&fill[nd], 1);
      csr_src[pos] = ns;
      csr_w[pos] = dinv[ns] * dinv[nd];
    }
  }
}

// ---------------- pre-split + transpose weights ----------------
__global__ __launch_bounds__(256) void wsplit_kernel(const float* __restrict__ W,
                                                     u16* __restrict__ Th,
                                                     u16* __restrict__ Tl,
                                                     int FIN, int FOUT) {
  int i = blockIdx.x * blockDim.x + threadIdx.x;
  if (i >= FIN * FOUT) return;
  int k = i / FOUT, c = i % FOUT;
  u16 h, l;
  split2(W[i], h, l);
  Th[(size_t)c * FIN + k] = h;
  Tl[(size_t)c * FIN + k] = l;
}

// ---------------- z = emb[nodelist[row]], split, compacted rows ----------------
__global__ __launch_bounds__(256) void embed_split_kernel(const int* __restrict__ nodelist,
                                                          const float* __restrict__ emb,
                                                          u16* __restrict__ Ah,
                                                          u16* __restrict__ Al,
                                                          const int* __restrict__ NmPtr) {
  int Nm = *NmPtr;
  int i = blockIdx.x * blockDim.x + threadIdx.x;
  int stride = gridDim.x * blockDim.x;
  int total = Nm * (HDIM / 4);
  for (int j = i; j < total; j += stride) {
    int row = j >> 4;
    int c = (j & 15) * 4;
    int xr = nodelist[row];
    float4 v = *(const float4*)&emb[(size_t)xr * HDIM + c];
    u16 h0, l0, h1, l1, h2, l2, h3, l3;
    split2(v.x, h0, l0); split2(v.y, h1, l1);
    split2(v.z, h2, l2); split2(v.w, h3, l3);
    uint2v hp = {(unsigned)h0 | ((unsigned)h1 << 16), (unsigned)h2 | ((unsigned)h3 << 16)};
    uint2v lp = {(unsigned)l0 | ((unsigned)l1 << 16), (unsigned)l2 | ((unsigned)l3 << 16)};
    *(uint2v*)&Ah[(size_t)row * HDIM + c] = hp;
    *(uint2v*)&Al[(size_t)row * HDIM + c] = lp;
  }
}

// ------- split-bf16 MFMA GEMM over compacted rows ----
template <int FIN, int FOUT>
__global__ __launch_bounds__(256) void gemm_split_kernel(const u16* __restrict__ Ah,
                                                         const u16* __restrict__ Al,
                                                         const u16* __restrict__ Wh,
                                                         const u16* __restrict__ Wl,
                                                         float* __restrict__ Out,
                                                         const int* __restrict__ NmPtr) {
  const int Nm = *NmPtr;
  const int r0 = blockIdx.x * 128, c0 = blockIdx.y * 64;
  if (r0 >= Nm) return;
  __shared__ u16 AH[8 * 128 * 8], AL[8 * 128 * 8];
  __shared__ u16 WH[8 * 64 * 8], WL[8 * 64 * 8];
  const int tid = threadIdx.x;
  const int lane = tid & 63, w = tid >> 6;
  const int l15 = lane & 15, l4 = lane >> 4;
  f32x4 acc[2][4] = {};

  for (int k0 = 0; k0 < FIN; k0 += 64) {
#pragma unroll
    for (int p = 0; p < 4; ++p) {
      int e = p * 2048 + tid * 8;
      int r = e >> 6, ke = e & 63;
      int g0 = ke >> 2;
      int h = (g0 >> 2) & 1;
      int gp = (g0 & 3) | ((g0 >> 3) << 2);
      uint2v vh0 = {0, 0}, vh1 = {0, 0}, vl0 = {0, 0}, vl1 = {0, 0};
      if (r0 + r < Nm) {
        size_t gbase = (size_t)(r0 + r) * FIN + k0 + ke;
        vh0 = *(const uint2v*)&Ah[gbase];
        vh1 = *(const uint2v*)&Ah[gbase + 4];
        vl0 = *(const uint2v*)&Al[gbase];
        vl1 = *(const uint2v*)&Al[gbase + 4];
      }
      *(uint2v*)&AH[((gp * 128 + r) * 8) + h * 4] = vh0;
      *(uint2v*)&AH[(((gp + 1) * 128 + r) * 8) + h * 4] = vh1;
      *(uint2v*)&AL[((gp * 128 + r) * 8) + h * 4] = vl0;
      *(uint2v*)&AL[(((gp + 1) * 128 + r) * 8) + h * 4] = vl1;
    }
#pragma unroll
    for (int p = 0; p < 2; ++p) {
      int e = p * 2048 + tid * 8;
      int c = e >> 6, ke = e & 63;
      int g0 = ke >> 2;
      int h = (g0 >> 2) & 1;
      int gp = (g0 & 3) | ((g0 >> 3) << 2);
      size_t gbase = (size_t)(c0 + c) * FIN + k0 + ke;
      uint2v vh0 = *(const uint2v*)&Wh[gbase];
      uint2v vh1 = *(const uint2v*)&Wh[gbase + 4];
      uint2v vl0 = *(const uint2v*)&Wl[gbase];
      uint2v vl1 = *(const uint2v*)&Wl[gbase + 4];
      *(uint2v*)&WH[((gp * 64 + c) * 8) + h * 4] = vh0;
      *(uint2v*)&WH[(((gp + 1) * 64 + c) * 8) + h * 4] = vh1;
      *(uint2v*)&WL[((gp * 64 + c) * 8) + h * 4] = vl0;
      *(uint2v*)&WL[(((gp + 1) * 64 + c) * 8) + h * 4] = vl1;
    }
    __syncthreads();
#pragma unroll
    for (int ko = 0; ko < 2; ++ko) {
      const int gb = ko * 4 + l4;
      short8 ah[2], al[2], wh[4], wl[4];
#pragma unroll
      for (int mi = 0; mi < 2; ++mi) {
        int slot = gb * 128 + (w * 32 + mi * 16 + l15);
        ah[mi] = *(const short8*)&AH[slot * 8];
        al[mi] = *(const short8*)&AL[slot * 8];
      }
#pragma unroll
      for (int ni = 0; ni < 4; ++ni) {
        int slot = gb * 64 + (ni * 16 + l15);
        wh[ni] = *(const short8*)&WH[slot * 8];
        wl[ni] = *(const short8*)&WL[slot * 8];
      }
#pragma unroll
      for (int mi = 0; mi < 2; ++mi)
#pragma unroll
        for (int ni = 0; ni < 4; ++ni) {
          acc[mi][ni] = __builtin_amdgcn_mfma_f32_16x16x32_bf16(ah[mi], wh[ni], acc[mi][ni], 0, 0, 0);
          acc[mi][ni] = __builtin_amdgcn_mfma_f32_16x16x32_bf16(ah[mi], wl[ni], acc[mi][ni], 0, 0, 0);
          acc[mi][ni] = __builtin_amdgcn_mfma_f32_16x16x32_bf16(al[mi], wh[ni], acc[mi][ni], 0, 0, 0);
        }
    }
    __syncthreads();
  }
#pragma unroll
  for (int mi = 0; mi < 2; ++mi)
#pragma unroll
    for (int ni = 0; ni < 4; ++ni)
#pragma unroll
      for (int j = 0; j < 4; ++j) {
        int row = r0 + w * 32 + mi * 16 + l4 * 4 + j;
        if (row < Nm) Out[(size_t)row * FOUT + c0 + ni * 16 + l15] = acc[mi][ni][j];
      }
}

// ---- pull aggregation (compacted), unroll-4 gathers, relu+split output ----
template <int FOUT>
__global__ __launch_bounds__(256) void aggregate_split_kernel(
    const float* __restrict__ HW, const int* __restrict__ rowstart,
    const int* __restrict__ csr_src, const float* __restrict__ csr_w,
    const float* __restrict__ dinv, const float* __restrict__ bias,
    u16* __restrict__ Ah, u16* __restrict__ Al, const int* __restrict__ NmPtr) {
  const int Nm = *NmPtr;
  const int lane = threadIdx.x & 63;
  const int wid = (int)((blockIdx.x * blockDim.x + threadIdx.x) >> 6);
  const int nw = (int)((gridDim.x * blockDim.x) >> 6);
  const bool act = (4 * lane) < FOUT;
  for (int r = wid; r < Nm; r += nw) {
    const int e0 = rowstart[r];
    const int e1 = rowstart[r + 1];
    float4 acc = {0.f, 0.f, 0.f, 0.f};
    if (act) {
      float di = dinv[r];
      float sn = di * di;
      float4 v = *(const float4*)&HW[(size_t)r * FOUT + 4 * lane];
      float4 bb = *(const float4*)&bias[4 * lane];
      acc.x = sn * v.x + bb.x; acc.y = sn * v.y + bb.y;
      acc.z = sn * v.z + bb.z; acc.w = sn * v.w + bb.w;
    }
    int e = e0;
    for (; e + 4 <= e1; e += 4) {
      int s0 = csr_src[e], s1 = csr_src[e + 1], s2 = csr_src[e + 2], s3 = csr_src[e + 3];
      float w0 = csr_w[e], w1 = csr_w[e + 1], w2 = csr_w[e + 2], w3 = csr_w[e + 3];
      if (act) {
        float4 v0 = *(const float4*)&HW[(size_t)s0 * FOUT + 4 * lane];
        float4 v1 = *(const float4*)&HW[(size_t)s1 * FOUT + 4 * lane];
        float4 v2 = *(const float4*)&HW[(size_t)s2 * FOUT + 4 * lane];
        float4 v3 = *(const float4*)&HW[(size_t)s3 * FOUT + 4 * lane];
        acc.x += w0 * v0.x + w1 * v1.x + w2 * v2.x + w3 * v3.x;
        acc.y += w0 * v0.y + w1 * v1.y + w2 * v2.y + w3 * v3.y;
        acc.z += w0 * v0.z + w1 * v1.z + w2 * v2.z + w3 * v3.z;
        acc.w += w0 * v0.w + w1 * v1.w + w2 * v2.w + w3 * v3.w;
      }
    }
    for (; e < e1; ++e) {
      int s = csr_src[e];
      float w = csr_w[e];
      if (act) {
        float4 v = *(const float4*)&HW[(size_t)s * FOUT + 4 * lane];
        acc.x += w * v.x; acc.y += w * v.y;
        acc.z += w * v.z; acc.w += w * v.w;
      }
    }
    if (act) {
      acc.x = fmaxf(acc.x, 0.f); acc.y = fmaxf(acc.y, 0.f);
      acc.z = fmaxf(acc.z, 0.f); acc.w = fmaxf(acc.w, 0.f);
      u16 h0, l0, h1, l1, h2, l2, h3, l3;
      split2(acc.x, h0, l0); split2(acc.y, h1, l1);
      split2(acc.z, h2, l2); split2(acc.w, h3, l3);
      uint2v hp = {(unsigned)h0 | ((unsigned)h1 << 16), (unsigned)h2 | ((unsigned)h3 << 16)};
      uint2v lp = {(unsigned)l0 | ((unsigned)l1 << 16), (unsigned)l2 | ((unsigned)l3 << 16)};
      *(uint2v*)&Ah[(size_t)r * FOUT + 4 * lane] = hp;
      *(uint2v*)&Al[(size_t)r * FOUT + 4 * lane] = lp;
    }
  }
}

// ---- layer-3 aggregation + pool: register pool accum, one reduce per block ----
__global__ __launch_bounds__(256) void agg3_pool_kernel(
    const float* __restrict__ HW, const int* __restrict__ rowstart,
    const int* __restrict__ csr_src, const float* __restrict__ csr_w,
    const float* __restrict__ dinv, const float* __restrict__ bias,
    float* __restrict__ pooled, const int* __restrict__ NmPtr) {
  const int Nm = *NmPtr;
  const int lane = threadIdx.x & 63;
  const int wid = (int)((blockIdx.x * blockDim.x + threadIdx.x) >> 6);
  const int nw = (int)((gridDim.x * blockDim.x) >> 6);
  const bool act = (4 * lane) < F3;
  float p0 = 0.f, p1 = 0.f, p2 = 0.f, p3 = 0.f;
  float4 bb = {0.f, 0.f, 0.f, 0.f};
  if (act) bb = *(const float4*)&bias[4 * lane];
  for (int r = wid; r < Nm; r += nw) {
    const int e0 = rowstart[r];
    const int e1 = rowstart[r + 1];
    float4 acc = {0.f, 0.f, 0.f, 0.f};
    if (act) {
      float di = dinv[r];
      float sn = di * di;
      float4 v = *(const float4*)&HW[(size_t)r * F3 + 4 * lane];
      acc.x = sn * v.x + bb.x; acc.y = sn * v.y + bb.y;
      acc.z = sn * v.z + bb.z; acc.w = sn * v.w + bb.w;
    }
    int e = e0;
    for (; e + 4 <= e1; e += 4) {
      int s0 = csr_src[e], s1 = csr_src[e + 1], s2 = csr_src[e + 2], s3 = csr_src[e + 3];
      float w0 = csr_w[e], w1 = csr_w[e + 1], w2 = csr_w[e + 2], w3 = csr_w[e + 3];
      if (act) {
        float4 v0 = *(const float4*)&HW[(size_t)s0 * F3 + 4 * lane];
        float4 v1 = *(const float4*)&HW[(size_t)s1 * F3 + 4 * lane];
        float4 v2 = *(const float4*)&HW[(size_t)s2 * F3 + 4 * lane];
        float4 v3 = *(const float4*)&HW[(size_t)s3 * F3 + 4 * lane];
        acc.x += w0 * v0.x + w1 * v1.x + w2 * v2.x + w3 * v3.x;
        acc.y += w0 * v0.y + w1 * v1.y + w2 * v2.y + w3 * v3.y;
        acc.z += w0 * v0.z + w1 * v1.z + w2 * v2.z + w3 * v3.z;
        acc.w += w0 * v0.w + w1 * v1.w + w2 * v2.w + w3 * v3.w;
      }
    }
    for (; e < e1; ++e) {
      int s = csr_src[e];
      float w = csr_w[e];
      if (act) {
        float4 v = *(const float4*)&HW[(size_t)s * F3 + 4 * lane];
        acc.x += w * v.x; acc.y += w * v.y;
        acc.z += w * v.z; acc.w += w * v.w;
      }
    }
    p0 += fmaxf(acc.x, 0.f); p1 += fmaxf(acc.y, 0.f);
    p2 += fmaxf(acc.z, 0.f); p3 += fmaxf(acc.w, 0.f);
  }
  __shared__ float pacc[F3];
  for (int i = threadIdx.x; i < F3; i += 256) pacc[i] = 0.0f;
  __syncthreads();
  if (act) {
    atomicAdd(&pacc[4 * lane + 0], p0);
    atomicAdd(&pacc[4 * lane + 1], p1);
    atomicAdd(&pacc[4 * lane + 2], p2);
    atomicAdd(&pacc[4 * lane + 3], p3);
  }
  __syncthreads();
  for (int i = threadIdx.x; i < F3; i += 256) atomicAdd(&pooled[i], pacc[i]);
}

// ---------------- phead = bh1 + (pooled/mcnt) @ Wh1[0:192,:] ----------------
__global__ __launch_bounds__(128) void phead_kernel(const float* __restrict__ pooled,
                                                    const float* __restrict__ mcnt,
                                                    const float* __restrict__ Wh1,
                                                    const float* __restrict__ bh1,
                                                    float* __restrict__ phead) {
  int t = threadIdx.x;
  float inv = 1.0f / *mcnt;
  float acc = bh1[t];
  for (int k = 0; k < F3; ++k) acc += pooled[k] * inv * Wh1[k * FH + t];
  phead[t] = acc;
}

// ---------------- head ----------------
__global__ __launch_bounds__(256) void head_kernel(const int* __restrict__ x,
                                                   const float* __restrict__ emb,
                                                   const float* __restrict__ Wh1,
                                                   const float* __restrict__ phead,
                                                   const float* __restrict__ gamma,
                                                   const float* __restrict__ beta,
                                                   const float* __restrict__ Wh2,
                                                   const float* __restrict__ bh2,
                                                   float* __restrict__ out, int N) {
  const int lane = threadIdx.x & 63;
  const int wid = (int)((blockIdx.x * blockDim.x + threadIdx.x) >> 6);
  const int nw = (int)((gridDim.x * blockDim.x) >> 6);
  const float bninv = 1.0f / sqrtf(1.0f + 1e-5f);
  const float ph0 = phead[lane], ph1 = phead[64 + lane];
  const float ga0 = gamma[lane] * bninv, ga1 = gamma[64 + lane] * bninv;
  const float be0 = beta[lane], be1 = beta[64 + lane];
  const float w20 = Wh2[lane], w21 = Wh2[64 + lane];
  const float bias2 = bh2[0];
  for (int r = wid; r < N; r += nw) {
    int xr = x[r];
    float ev = emb[(size_t)xr * HDIM + lane];
    float a0 = 0.f, a1 = 0.f;
#pragma unroll
    for (int k = 0; k < HDIM; ++k) {
      float zk = __shfl(ev, k);
      a0 += zk * Wh1[(size_t)(F3 + k) * FH + lane];
      a1 += zk * Wh1[(size_t)(F3 + k) * FH + 64 + lane];
    }
    float h0 = fmaxf(ph0 + a0, 0.f) * ga0 + be0;
    float h1 = fmaxf(ph1 + a1, 0.f) * ga1 + be1;
    float contrib = h0 * w20 + h1 * w21;
#pragma unroll
    for (int off = 32; off; off >>= 1) contrib += __shfl_xor(contrib, off);
    if (lane == 0) out[r] = contrib + bias2;
  }
}

extern "C" void kernel_launch(void* const* d_in, const int* in_sizes, int n_in,
                              void* d_out, int out_size, void* d_ws, size_t ws_size,
                              hipStream_t stream) {
  const int N = in_sizes[0];
  const int E = in_sizes[1] / 2;

  const int* x = (const int*)d_in[0];
  const int* ei = (const int*)d_in[1];
  const int* nt = (const int*)d_in[2];
  const float* emb = (const float*)d_in[3];
  const float* W1 = (const float*)d_in[4];
  const float* b1 = (const float*)d_in[5];
  const float* W2 = (const float*)d_in[6];
  const float* b2 = (const float*)d_in[7];
  const float* W3 = (const float*)d_in[8];
  const float* b3 = (const float*)d_in[9];
  const float* Wh1 = (const float*)d_in[10];
  const float* bh1 = (const float*)d_in[11];
  const float* gamma = (const float*)d_in[12];
  const float* beta = (const float*)d_in[13];
  const float* Wh2 = (const float*)d_in[14];
  const float* bh2 = (const float*)d_in[15];
  float* out = (float*)d_out;

  // workspace layout
  float* ws = (float*)d_ws;
  float* B = ws;                                   // N*256 fp32 (hw)
  u16* Ahi = (u16*)(B + (size_t)N * 256);          // N*256 bf16-hi
  u16* Alo = Ahi + (size_t)N * 256;                // N*256 bf16-lo
  u16* WTh = Alo + (size_t)N * 256;                // 131072
  u16* WTl = WTh + 131072;                         // 131072
  float* dinv = (float*)(WTl + 131072);            // N
  float* csr_w = dinv + N;                         // E
  int* csr_src = (int*)(csr_w + E);                // E
  int* counts = csr_src + E;                       // N
  int* fill = counts + N;                          // N
  int* rowstart = fill + N;                        // N+1
  int* newidx = rowstart + N + 2;                  // N
  int* nodelist = newidx + N;                      // N
  int* blocksum = nodelist + N;                    // 256
  int* NmInt = blocksum + 256;                     // 1
  float* pooled = (float*)(NmInt + 1);             // 192
  float* phead = pooled + F3;                      // 128
  float* mcnt = phead + FH;                        // 1
  (void)ws_size; (void)n_in; (void)out_size;

  u16* W1Th = WTh,        * W1Tl = WTl;
  u16* W2Th = WTh + 16384,  * W2Tl = WTl + 16384;
  u16* W3Th = WTh + 81920,  * W3Tl = WTl + 81920;

  const int rowBlocks = (N + 127) / 128;
  const int aggBlocks = (N + 3) / 4;
  const int scanBlocks = (N + 1023) / 1024;

  init_kernel<<<256, 256, 0, stream>>>(counts, pooled, N);
  // mask scan: newidx/nodelist/Nm/mcnt
  scan_p1<0><<<scanBlocks, 256, 0, stream>>>(nt, blocksum, N);
  scan_p2<<<1, 64, 0, stream>>>(blocksum, scanBlocks);
  scan_p3<0><<<scanBlocks, 256, 0, stream>>>(nt, blocksum, newidx, nodelist, NmInt, mcnt, N);
  count_kernel<<<1024, 256, 0, stream>>>(ei, nt, newidx, counts, E);
  dinv_kernel<<<256, 256, 0, stream>>>(counts, dinv, NmInt);
  // counts scan: rowstart/fill
  scan_p1<1><<<scanBlocks, 256, 0, stream>>>(counts, blocksum, N);
  scan_p2<<<1, 64, 0, stream>>>(blocksum, scanBlocks);
  scan_p3<1><<<scanBlocks, 256, 0, stream>>>(counts, blocksum, rowstart, fill, NmInt, mcnt, N);
  fill_kernel<<<1024, 256, 0, stream>>>(ei, nt, newidx, dinv, fill, csr_src, csr_w, E);
  wsplit_kernel<<<(HDIM * F1 + 255) / 256, 256, 0, stream>>>(W1, W1Th, W1Tl, HDIM, F1);
  wsplit_kernel<<<(F1 * F1 + 255) / 256, 256, 0, stream>>>(W2, W2Th, W2Tl, F1, F1);
  wsplit_kernel<<<(F1 * F3 + 255) / 256, 256, 0, stream>>>(W3, W3Th, W3Tl, F1, F3);
  embed_split_kernel<<<1024, 256, 0, stream>>>(nodelist, emb, Ahi, Alo, NmInt);

  // layer 1
  gemm_split_kernel<HDIM, F1><<<dim3(rowBlocks, F1 / 64), 256, 0, stream>>>(Ahi, Alo, W1Th, W1Tl, B, NmInt);
  aggregate_split_kernel<F1><<<aggBlocks, 256, 0, stream>>>(B, rowstart, csr_src, csr_w, dinv, b1, Ahi, Alo, NmInt);

  // layer 2
  gemm_split_kernel<F1, F1><<<dim3(rowBlocks, F1 / 64), 256, 0, stream>>>(Ahi, Alo, W2Th, W2Tl, B, NmInt);
  aggregate_split_kernel<F1><<<aggBlocks, 256, 0, stream>>>(B, rowstart, csr_src, csr_w, dinv, b2, Ahi, Alo, NmInt);

  // layer 3 (+ fused masked pool; z3 never materialized)
  gemm_split_kernel<F1, F3><<<dim3(rowBlocks, F3 / 64), 256, 0, stream>>>(Ahi, Alo, W3Th, W3Tl, B, NmInt);
  agg3_pool_kernel<<<1024, 256, 0, stream>>>(B, rowstart, csr_src, csr_w, dinv, b3, pooled, NmInt);

  // head
  phead_kernel<<<1, 128, 0, stream>>>(pooled, mcnt, Wh1, bh1, phead);
  head_kernel<<<768, 256, 0, stream>>>(x, emb, Wh1, phead, gamma, beta, Wh2, bh2, out, N);
}

// Round 6
// 290.128 us; speedup vs baseline: 9.9077x; 1.1196x over previous
//
#include <hip/hip_runtime.h>

#define HDIM 64
#define F1 256
#define F3 192
#define FH 128

typedef unsigned short u16;
typedef __attribute__((ext_vector_type(8))) short short8;
typedef __attribute__((ext_vector_type(4))) float f32x4;
typedef __attribute__((ext_vector_type(2))) unsigned int uint2v;

// fp32 -> bf16(hi) + bf16(lo), both RNE
__device__ __forceinline__ void split2(float v, u16& h, u16& l) {
  unsigned u = __float_as_uint(v);
  unsigned r = u + 0x7FFFu + ((u >> 16) & 1u);
  h = (u16)(r >> 16);
  float fh = __uint_as_float(((unsigned)h) << 16);
  float res = v - fh;
  unsigned u2 = __float_as_uint(res);
  unsigned r2 = u2 + 0x7FFFu + ((u2 >> 16) & 1u);
  l = (u16)(r2 >> 16);
}

// ---------------- init ----------------
__global__ __launch_bounds__(256) void init_kernel(int* counts, float* pooled, int N) {
  int i = blockIdx.x * blockDim.x + threadIdx.x;
  int stride = gridDim.x * blockDim.x;
  for (int j = i; j < N; j += stride) counts[j] = 0;
  if (i < F3) pooled[i] = 0.0f;
}

// ------------- generic 3-phase exclusive scan, MODE 0: mask(nt==0), 1: counts ----
template <int MODE>
__global__ __launch_bounds__(256) void scan_p1(const int* __restrict__ in,
                                               int* __restrict__ blocksum, int N) {
  __shared__ int wsum[4];
  int base = blockIdx.x * 1024 + threadIdx.x * 4;
  int s = 0;
#pragma unroll
  for (int j = 0; j < 4; ++j) {
    int i = base + j;
    if (i < N) s += (MODE == 0) ? (in[i] == 0 ? 1 : 0) : in[i];
  }
#pragma unroll
  for (int off = 32; off; off >>= 1) s += __shfl_xor(s, off);
  if ((threadIdx.x & 63) == 0) wsum[threadIdx.x >> 6] = s;
  __syncthreads();
  if (threadIdx.x == 0)
    blocksum[blockIdx.x] = wsum[0] + wsum[1] + wsum[2] + wsum[3];
}

__global__ __launch_bounds__(64) void scan_p2(int* __restrict__ blocksum, int G) {
  int tid = threadIdx.x;
  int run = 0;
  for (int b0 = 0; b0 < G; b0 += 64) {
    int i = b0 + tid;
    int orig = (i < G) ? blocksum[i] : 0;
    int v = orig;
#pragma unroll
    for (int off = 1; off < 64; off <<= 1) {
      int t = __shfl_up(v, off);
      if (tid >= off) v += t;
    }
    if (i < G) blocksum[i] = run + v - orig;
    run += __shfl(v, 63);
  }
}

// MODE 0: out0=newidx, out1=nodelist, writes NmInt/mcnt.  MODE 1: out0=rowstart, out1=fill.
template <int MODE>
__global__ __launch_bounds__(256) void scan_p3(const int* __restrict__ in,
                                               const int* __restrict__ blocksum,
                                               int* __restrict__ out0,
                                               int* __restrict__ out1,
                                               int* __restrict__ NmInt,
                                               float* __restrict__ mcnt, int N) {
  __shared__ int wsum[4];
  const int tid = threadIdx.x;
  int base = blockIdx.x * 1024 + tid * 4;
  int c[4];
  int tsum = 0;
#pragma unroll
  for (int j = 0; j < 4; ++j) {
    int i = base + j;
    c[j] = (i < N) ? ((MODE == 0) ? (in[i] == 0 ? 1 : 0) : in[i]) : 0;
    tsum += c[j];
  }
  int v = tsum;
#pragma unroll
  for (int off = 1; off < 64; off <<= 1) {
    int t = __shfl_up(v, off);
    if ((tid & 63) >= off) v += t;
  }
  int wexcl = v - tsum;
  if ((tid & 63) == 63) wsum[tid >> 6] = v;
  __syncthreads();
  int wbase = 0;
  int wv = tid >> 6;
#pragma unroll
  for (int j = 0; j < 4; ++j)
    if (j < wv) wbase += wsum[j];
  int off0 = blocksum[blockIdx.x] + wbase + wexcl;
#pragma unroll
  for (int j = 0; j < 4; ++j) {
    int i = base + j;
    if (i < N) {
      if (MODE == 0) {
        out0[i] = off0;
        if (c[j]) out1[off0] = i;
        off0 += c[j];
        if (i == N - 1) { *NmInt = off0; *mcnt = (float)off0; }
      } else {
        out0[i] = off0;
        out1[i] = off0;
        off0 += c[j];
        if (i == N - 1) out0[N] = off0;
      }
    }
  }
}

// ---------------- masked in-degree in COMPACTED dst space ----------------
__global__ __launch_bounds__(256) void count_kernel(const int* __restrict__ ei,
                                                    const int* __restrict__ nt,
                                                    const int* __restrict__ newidx,
                                                    int* __restrict__ counts, int E) {
  int i = blockIdx.x * blockDim.x + threadIdx.x;
  int stride = gridDim.x * blockDim.x;
  for (int e = i; e < E; e += stride) {
    int s = ei[e], d = ei[E + e];
    if (nt[s] == 0 && nt[d] == 0) atomicAdd(&counts[newidx[d]], 1);
  }
}

// ---------------- counts -> dinv (compacted) ----------------
__global__ __launch_bounds__(256) void dinv_kernel(const int* __restrict__ counts,
                                                   float* __restrict__ dinv,
                                                   const int* __restrict__ NmPtr) {
  int Nm = *NmPtr;
  int i = blockIdx.x * blockDim.x + threadIdx.x;
  int stride = gridDim.x * blockDim.x;
  for (int j = i; j < Nm; j += stride) dinv[j] = rsqrtf(1.0f + (float)counts[j]);
}

// ---------------- bucket active edges by compacted dst ----------------
__global__ __launch_bounds__(256) void fill_kernel(const int* __restrict__ ei,
                                                   const int* __restrict__ nt,
                                                   const int* __restrict__ newidx,
                                                   const float* __restrict__ dinv,
                                                   int* __restrict__ fill,
                                                   int* __restrict__ csr_src,
                                                   float* __restrict__ csr_w, int E) {
  int i = blockIdx.x * blockDim.x + threadIdx.x;
  int stride = gridDim.x * blockDim.x;
  for (int e = i; e < E; e += stride) {
    int s = ei[e], d = ei[E + e];
    if (nt[s] == 0 && nt[d] == 0) {
      int ns = newidx[s], nd = newidx[d];
      int pos = atomicAdd(&fill[nd], 1);
      csr_src[pos] = ns;
      csr_w[pos] = dinv[ns] * dinv[nd];
    }
  }
}

// ---------------- pre-split + transpose weights ----------------
__global__ __launch_bounds__(256) void wsplit_kernel(const float* __restrict__ W,
                                                     u16* __restrict__ Th,
                                                     u16* __restrict__ Tl,
                                                     int FIN, int FOUT) {
  int i = blockIdx.x * blockDim.x + threadIdx.x;
  if (i >= FIN * FOUT) return;
  int k = i / FOUT, c = i % FOUT;
  u16 h, l;
  split2(W[i], h, l);
  Th[(size_t)c * FIN + k] = h;
  Tl[(size_t)c * FIN + k] = l;
}

// ---------------- z = emb[idx[row]], split, row count from device ptr ------------
__global__ __launch_bounds__(256) void embed_split_kernel(const int* __restrict__ nodelist,
                                                          const float* __restrict__ emb,
                                                          u16* __restrict__ Ah,
                                                          u16* __restrict__ Al,
                                                          const int* __restrict__ NmPtr) {
  int Nm = *NmPtr;
  int i = blockIdx.x * blockDim.x + threadIdx.x;
  int stride = gridDim.x * blockDim.x;
  int total = Nm * (HDIM / 4);
  for (int j = i; j < total; j += stride) {
    int row = j >> 4;
    int c = (j & 15) * 4;
    int xr = nodelist[row];
    float4 v = *(const float4*)&emb[(size_t)xr * HDIM + c];
    u16 h0, l0, h1, l1, h2, l2, h3, l3;
    split2(v.x, h0, l0); split2(v.y, h1, l1);
    split2(v.z, h2, l2); split2(v.w, h3, l3);
    uint2v hp = {(unsigned)h0 | ((unsigned)h1 << 16), (unsigned)h2 | ((unsigned)h3 << 16)};
    uint2v lp = {(unsigned)l0 | ((unsigned)l1 << 16), (unsigned)l2 | ((unsigned)l3 << 16)};
    *(uint2v*)&Ah[(size_t)row * HDIM + c] = hp;
    *(uint2v*)&Al[(size_t)row * HDIM + c] = lp;
  }
}

// ---- same, but row count by value (full-N head input) ----
__global__ __launch_bounds__(256) void embed_split_all_kernel(const int* __restrict__ idx,
                                                              const float* __restrict__ emb,
                                                              u16* __restrict__ Ah,
                                                              u16* __restrict__ Al, int N) {
  int i = blockIdx.x * blockDim.x + threadIdx.x;
  int stride = gridDim.x * blockDim.x;
  int total = N * (HDIM / 4);
  for (int j = i; j < total; j += stride) {
    int row = j >> 4;
    int c = (j & 15) * 4;
    int xr = idx[row];
    float4 v = *(const float4*)&emb[(size_t)xr * HDIM + c];
    u16 h0, l0, h1, l1, h2, l2, h3, l3;
    split2(v.x, h0, l0); split2(v.y, h1, l1);
    split2(v.z, h2, l2); split2(v.w, h3, l3);
    uint2v hp = {(unsigned)h0 | ((unsigned)h1 << 16), (unsigned)h2 | ((unsigned)h3 << 16)};
    uint2v lp = {(unsigned)l0 | ((unsigned)l1 << 16), (unsigned)l2 | ((unsigned)l3 << 16)};
    *(uint2v*)&Ah[(size_t)row * HDIM + c] = hp;
    *(uint2v*)&Al[(size_t)row * HDIM + c] = lp;
  }
}

// ------- split-bf16 MFMA GEMM over compacted rows ----
template <int FIN, int FOUT>
__global__ __launch_bounds__(256) void gemm_split_kernel(const u16* __restrict__ Ah,
                                                         const u16* __restrict__ Al,
                                                         const u16* __restrict__ Wh,
                                                         const u16* __restrict__ Wl,
                                                         float* __restrict__ Out,
                                                         const int* __restrict__ NmPtr) {
  const int Nm = *NmPtr;
  const int r0 = blockIdx.x * 128, c0 = blockIdx.y * 64;
  if (r0 >= Nm) return;
  __shared__ u16 AH[8 * 128 * 8], AL[8 * 128 * 8];
  __shared__ u16 WH[8 * 64 * 8], WL[8 * 64 * 8];
  const int tid = threadIdx.x;
  const int lane = tid & 63, w = tid >> 6;
  const int l15 = lane & 15, l4 = lane >> 4;
  f32x4 acc[2][4] = {};

  for (int k0 = 0; k0 < FIN; k0 += 64) {
#pragma unroll
    for (int p = 0; p < 4; ++p) {
      int e = p * 2048 + tid * 8;
      int r = e >> 6, ke = e & 63;
      int g0 = ke >> 2;
      int h = (g0 >> 2) & 1;
      int gp = (g0 & 3) | ((g0 >> 3) << 2);
      uint2v vh0 = {0, 0}, vh1 = {0, 0}, vl0 = {0, 0}, vl1 = {0, 0};
      if (r0 + r < Nm) {
        size_t gbase = (size_t)(r0 + r) * FIN + k0 + ke;
        vh0 = *(const uint2v*)&Ah[gbase];
        vh1 = *(const uint2v*)&Ah[gbase + 4];
        vl0 = *(const uint2v*)&Al[gbase];
        vl1 = *(const uint2v*)&Al[gbase + 4];
      }
      *(uint2v*)&AH[((gp * 128 + r) * 8) + h * 4] = vh0;
      *(uint2v*)&AH[(((gp + 1) * 128 + r) * 8) + h * 4] = vh1;
      *(uint2v*)&AL[((gp * 128 + r) * 8) + h * 4] = vl0;
      *(uint2v*)&AL[(((gp + 1) * 128 + r) * 8) + h * 4] = vl1;
    }
#pragma unroll
    for (int p = 0; p < 2; ++p) {
      int e = p * 2048 + tid * 8;
      int c = e >> 6, ke = e & 63;
      int g0 = ke >> 2;
      int h = (g0 >> 2) & 1;
      int gp = (g0 & 3) | ((g0 >> 3) << 2);
      size_t gbase = (size_t)(c0 + c) * FIN + k0 + ke;
      uint2v vh0 = *(const uint2v*)&Wh[gbase];
      uint2v vh1 = *(const uint2v*)&Wh[gbase + 4];
      uint2v vl0 = *(const uint2v*)&Wl[gbase];
      uint2v vl1 = *(const uint2v*)&Wl[gbase + 4];
      *(uint2v*)&WH[((gp * 64 + c) * 8) + h * 4] = vh0;
      *(uint2v*)&WH[(((gp + 1) * 64 + c) * 8) + h * 4] = vh1;
      *(uint2v*)&WL[((gp * 64 + c) * 8) + h * 4] = vl0;
      *(uint2v*)&WL[(((gp + 1) * 64 + c) * 8) + h * 4] = vl1;
    }
    __syncthreads();
#pragma unroll
    for (int ko = 0; ko < 2; ++ko) {
      const int gb = ko * 4 + l4;
      short8 ah[2], al[2], wh[4], wl[4];
#pragma unroll
      for (int mi = 0; mi < 2; ++mi) {
        int slot = gb * 128 + (w * 32 + mi * 16 + l15);
        ah[mi] = *(const short8*)&AH[slot * 8];
        al[mi] = *(const short8*)&AL[slot * 8];
      }
#pragma unroll
      for (int ni = 0; ni < 4; ++ni) {
        int slot = gb * 64 + (ni * 16 + l15);
        wh[ni] = *(const short8*)&WH[slot * 8];
        wl[ni] = *(const short8*)&WL[slot * 8];
      }
#pragma unroll
      for (int mi = 0; mi < 2; ++mi)
#pragma unroll
        for (int ni = 0; ni < 4; ++ni) {
          acc[mi][ni] = __builtin_amdgcn_mfma_f32_16x16x32_bf16(ah[mi], wh[ni], acc[mi][ni], 0, 0, 0);
          acc[mi][ni] = __builtin_amdgcn_mfma_f32_16x16x32_bf16(ah[mi], wl[ni], acc[mi][ni], 0, 0, 0);
          acc[mi][ni] = __builtin_amdgcn_mfma_f32_16x16x32_bf16(al[mi], wh[ni], acc[mi][ni], 0, 0, 0);
        }
    }
    __syncthreads();
  }
#pragma unroll
  for (int mi = 0; mi < 2; ++mi)
#pragma unroll
    for (int ni = 0; ni < 4; ++ni)
#pragma unroll
      for (int j = 0; j < 4; ++j) {
        int row = r0 + w * 32 + mi * 16 + l4 * 4 + j;
        if (row < Nm) Out[(size_t)row * FOUT + c0 + ni * 16 + l15] = acc[mi][ni][j];
      }
}

// ---- pull aggregation (compacted), unroll-4 gathers, relu+split output ----
template <int FOUT>
__global__ __launch_bounds__(256) void aggregate_split_kernel(
    const float* __restrict__ HW, const int* __restrict__ rowstart,
    const int* __restrict__ csr_src, const float* __restrict__ csr_w,
    const float* __restrict__ dinv, const float* __restrict__ bias,
    u16* __restrict__ Ah, u16* __restrict__ Al, const int* __restrict__ NmPtr) {
  const int Nm = *NmPtr;
  const int lane = threadIdx.x & 63;
  const int wid = (int)((blockIdx.x * blockDim.x + threadIdx.x) >> 6);
  const int nw = (int)((gridDim.x * blockDim.x) >> 6);
  const bool act = (4 * lane) < FOUT;
  for (int r = wid; r < Nm; r += nw) {
    const int e0 = rowstart[r];
    const int e1 = rowstart[r + 1];
    float4 acc = {0.f, 0.f, 0.f, 0.f};
    if (act) {
      float di = dinv[r];
      float sn = di * di;
      float4 v = *(const float4*)&HW[(size_t)r * FOUT + 4 * lane];
      float4 bb = *(const float4*)&bias[4 * lane];
      acc.x = sn * v.x + bb.x; acc.y = sn * v.y + bb.y;
      acc.z = sn * v.z + bb.z; acc.w = sn * v.w + bb.w;
    }
    int e = e0;
    for (; e + 4 <= e1; e += 4) {
      int s0 = csr_src[e], s1 = csr_src[e + 1], s2 = csr_src[e + 2], s3 = csr_src[e + 3];
      float w0 = csr_w[e], w1 = csr_w[e + 1], w2 = csr_w[e + 2], w3 = csr_w[e + 3];
      if (act) {
        float4 v0 = *(const float4*)&HW[(size_t)s0 * FOUT + 4 * lane];
        float4 v1 = *(const float4*)&HW[(size_t)s1 * FOUT + 4 * lane];
        float4 v2 = *(const float4*)&HW[(size_t)s2 * FOUT + 4 * lane];
        float4 v3 = *(const float4*)&HW[(size_t)s3 * FOUT + 4 * lane];
        acc.x += w0 * v0.x + w1 * v1.x + w2 * v2.x + w3 * v3.x;
        acc.y += w0 * v0.y + w1 * v1.y + w2 * v2.y + w3 * v3.y;
        acc.z += w0 * v0.z + w1 * v1.z + w2 * v2.z + w3 * v3.z;
        acc.w += w0 * v0.w + w1 * v1.w + w2 * v2.w + w3 * v3.w;
      }
    }
    for (; e < e1; ++e) {
      int s = csr_src[e];
      float w = csr_w[e];
      if (act) {
        float4 v = *(const float4*)&HW[(size_t)s * FOUT + 4 * lane];
        acc.x += w * v.x; acc.y += w * v.y;
        acc.z += w * v.z; acc.w += w * v.w;
      }
    }
    if (act) {
      acc.x = fmaxf(acc.x, 0.f); acc.y = fmaxf(acc.y, 0.f);
      acc.z = fmaxf(acc.z, 0.f); acc.w = fmaxf(acc.w, 0.f);
      u16 h0, l0, h1, l1, h2, l2, h3, l3;
      split2(acc.x, h0, l0); split2(acc.y, h1, l1);
      split2(acc.z, h2, l2); split2(acc.w, h3, l3);
      uint2v hp = {(unsigned)h0 | ((unsigned)h1 << 16), (unsigned)h2 | ((unsigned)h3 << 16)};
      uint2v lp = {(unsigned)l0 | ((unsigned)l1 << 16), (unsigned)l2 | ((unsigned)l3 << 16)};
      *(uint2v*)&Ah[(size_t)r * FOUT + 4 * lane] = hp;
      *(uint2v*)&Al[(size_t)r * FOUT + 4 * lane] = lp;
    }
  }
}

// ---- layer-3 aggregation + pool: register pool accum, one reduce per block ----
__global__ __launch_bounds__(256) void agg3_pool_kernel(
    const float* __restrict__ HW, const int* __restrict__ rowstart,
    const int* __restrict__ csr_src, const float* __restrict__ csr_w,
    const float* __restrict__ dinv, const float* __restrict__ bias,
    float* __restrict__ pooled, const int* __restrict__ NmPtr) {
  const int Nm = *NmPtr;
  const int lane = threadIdx.x & 63;
  const int wid = (int)((blockIdx.x * blockDim.x + threadIdx.x) >> 6);
  const int nw = (int)((gridDim.x * blockDim.x) >> 6);
  const bool act = (4 * lane) < F3;
  float p0 = 0.f, p1 = 0.f, p2 = 0.f, p3 = 0.f;
  float4 bb = {0.f, 0.f, 0.f, 0.f};
  if (act) bb = *(const float4*)&bias[4 * lane];
  for (int r = wid; r < Nm; r += nw) {
    const int e0 = rowstart[r];
    const int e1 = rowstart[r + 1];
    float4 acc = {0.f, 0.f, 0.f, 0.f};
    if (act) {
      float di = dinv[r];
      float sn = di * di;
      float4 v = *(const float4*)&HW[(size_t)r * F3 + 4 * lane];
      acc.x = sn * v.x + bb.x; acc.y = sn * v.y + bb.y;
      acc.z = sn * v.z + bb.z; acc.w = sn * v.w + bb.w;
    }
    int e = e0;
    for (; e + 4 <= e1; e += 4) {
      int s0 = csr_src[e], s1 = csr_src[e + 1], s2 = csr_src[e + 2], s3 = csr_src[e + 3];
      float w0 = csr_w[e], w1 = csr_w[e + 1], w2 = csr_w[e + 2], w3 = csr_w[e + 3];
      if (act) {
        float4 v0 = *(const float4*)&HW[(size_t)s0 * F3 + 4 * lane];
        float4 v1 = *(const float4*)&HW[(size_t)s1 * F3 + 4 * lane];
        float4 v2 = *(const float4*)&HW[(size_t)s2 * F3 + 4 * lane];
        float4 v3 = *(const float4*)&HW[(size_t)s3 * F3 + 4 * lane];
        acc.x += w0 * v0.x + w1 * v1.x + w2 * v2.x + w3 * v3.x;
        acc.y += w0 * v0.y + w1 * v1.y + w2 * v2.y + w3 * v3.y;
        acc.z += w0 * v0.z + w1 * v1.z + w2 * v2.z + w3 * v3.z;
        acc.w += w0 * v0.w + w1 * v1.w + w2 * v2.w + w3 * v3.w;
      }
    }
    for (; e < e1; ++e) {
      int s = csr_src[e];
      float w = csr_w[e];
      if (act) {
        float4 v = *(const float4*)&HW[(size_t)s * F3 + 4 * lane];
        acc.x += w * v.x; acc.y += w * v.y;
        acc.z += w * v.z; acc.w += w * v.w;
      }
    }
    p0 += fmaxf(acc.x, 0.f); p1 += fmaxf(acc.y, 0.f);
    p2 += fmaxf(acc.z, 0.f); p3 += fmaxf(acc.w, 0.f);
  }
  __shared__ float pacc[F3];
  for (int i = threadIdx.x; i < F3; i += 256) pacc[i] = 0.0f;
  __syncthreads();
  if (act) {
    atomicAdd(&pacc[4 * lane + 0], p0);
    atomicAdd(&pacc[4 * lane + 1], p1);
    atomicAdd(&pacc[4 * lane + 2], p2);
    atomicAdd(&pacc[4 * lane + 3], p3);
  }
  __syncthreads();
  for (int i = threadIdx.x; i < F3; i += 256) atomicAdd(&pooled[i], pacc[i]);
}

// ------- phead = bh1 + (pooled/mcnt) @ Wh1[0:192,:]; also gw, hcst -------
__global__ __launch_bounds__(128) void phead_kernel(const float* __restrict__ pooled,
                                                    const float* __restrict__ mcnt,
                                                    const float* __restrict__ Wh1,
                                                    const float* __restrict__ bh1,
                                                    const float* __restrict__ gamma,
                                                    const float* __restrict__ beta,
                                                    const float* __restrict__ Wh2,
                                                    const float* __restrict__ bh2,
                                                    float* __restrict__ phead,
                                                    float* __restrict__ gw,
                                                    float* __restrict__ hcst) {
  int t = threadIdx.x;
  float inv = 1.0f / *mcnt;
  float acc = bh1[t];
  for (int k = 0; k < F3; ++k) acc += pooled[k] * inv * Wh1[k * FH + t];
  phead[t] = acc;
  const float bninv = 1.0f / sqrtf(1.0f + 1e-5f);
  float w2 = Wh2[t];
  gw[t] = gamma[t] * bninv * w2;
  __shared__ float red[FH];
  red[t] = beta[t] * w2;
  __syncthreads();
  if (t == 0) {
    float s = bh2[0];
    for (int i = 0; i < FH; ++i) s += red[i];
    *hcst = s;
  }
}

// ---- MFMA head: out[r] = sum_c relu(emb@Wh1tail + ph)[c] * gw[c] + hcst ----
// 128-row tiles, 4 waves x 32 rows, FOUT=128, K=64. Fragments from global (no LDS).
__global__ __launch_bounds__(256) void head_mfma_kernel(
    const u16* __restrict__ EAh, const u16* __restrict__ EAl,
    const u16* __restrict__ Hh, const u16* __restrict__ Hl,
    const float* __restrict__ phead, const float* __restrict__ gw,
    const float* __restrict__ hcst, float* __restrict__ out, int N) {
  const int tid = threadIdx.x;
  const int lane = tid & 63, w = tid >> 6;
  const int l15 = lane & 15, l4 = lane >> 4;
  const int r0 = blockIdx.x * 128;
  f32x4 acc[2][8] = {};
  const short8 zfrag = {};

#pragma unroll
  for (int ko = 0; ko < 2; ++ko) {
    const int kb = 32 * ko + 4 * l4;
    short8 bh[8], bl[8], ah[2], al[2];
#pragma unroll
    for (int ni = 0; ni < 8; ++ni) {
      int col = ni * 16 + l15;
      const u16* p = &Hh[col * 64 + kb];
      ((uint2v*)&bh[ni])[0] = *(const uint2v*)p;
      ((uint2v*)&bh[ni])[1] = *(const uint2v*)(p + 16);
      const u16* q = &Hl[col * 64 + kb];
      ((uint2v*)&bl[ni])[0] = *(const uint2v*)q;
      ((uint2v*)&bl[ni])[1] = *(const uint2v*)(q + 16);
    }
#pragma unroll
    for (int mi = 0; mi < 2; ++mi) {
      int row = r0 + w * 32 + mi * 16 + l15;
      if (row < N) {
        const u16* p = &EAh[(size_t)row * 64 + kb];
        ((uint2v*)&ah[mi])[0] = *(const uint2v*)p;
        ((uint2v*)&ah[mi])[1] = *(const uint2v*)(p + 16);
        const u16* q = &EAl[(size_t)row * 64 + kb];
        ((uint2v*)&al[mi])[0] = *(const uint2v*)q;
        ((uint2v*)&al[mi])[1] = *(const uint2v*)(q + 16);
      } else {
        ah[mi] = zfrag;
        al[mi] = zfrag;
      }
    }
#pragma unroll
    for (int mi = 0; mi < 2; ++mi)
#pragma unroll
      for (int ni = 0; ni < 8; ++ni) {
        acc[mi][ni] = __builtin_amdgcn_mfma_f32_16x16x32_bf16(ah[mi], bh[ni], acc[mi][ni], 0, 0, 0);
        acc[mi][ni] = __builtin_amdgcn_mfma_f32_16x16x32_bf16(ah[mi], bl[ni], acc[mi][ni], 0, 0, 0);
        acc[mi][ni] = __builtin_amdgcn_mfma_f32_16x16x32_bf16(al[mi], bh[ni], acc[mi][ni], 0, 0, 0);
      }
  }

  const float hc = *hcst;
  float ph[8], g[8];
#pragma unroll
  for (int ni = 0; ni < 8; ++ni) {
    int col = ni * 16 + l15;
    ph[ni] = phead[col];
    g[ni] = gw[col];
  }
#pragma unroll
  for (int mi = 0; mi < 2; ++mi)
#pragma unroll
    for (int j = 0; j < 4; ++j) {
      float s = 0.f;
#pragma unroll
      for (int ni = 0; ni < 8; ++ni)
        s += fmaxf(acc[mi][ni][j] + ph[ni], 0.f) * g[ni];
#pragma unroll
      for (int off = 1; off < 16; off <<= 1) s += __shfl_xor(s, off);
      int row = r0 + w * 32 + mi * 16 + l4 * 4 + j;
      if (l15 == 0 && row < N) out[row] = s + hc;
    }
}

extern "C" void kernel_launch(void* const* d_in, const int* in_sizes, int n_in,
                              void* d_out, int out_size, void* d_ws, size_t ws_size,
                              hipStream_t stream) {
  const int N = in_sizes[0];
  const int E = in_sizes[1] / 2;

  const int* x = (const int*)d_in[0];
  const int* ei = (const int*)d_in[1];
  const int* nt = (const int*)d_in[2];
  const float* emb = (const float*)d_in[3];
  const float* W1 = (const float*)d_in[4];
  const float* b1 = (const float*)d_in[5];
  const float* W2 = (const float*)d_in[6];
  const float* b2 = (const float*)d_in[7];
  const float* W3 = (const float*)d_in[8];
  const float* b3 = (const float*)d_in[9];
  const float* Wh1 = (const float*)d_in[10];
  const float* bh1 = (const float*)d_in[11];
  const float* gamma = (const float*)d_in[12];
  const float* beta = (const float*)d_in[13];
  const float* Wh2 = (const float*)d_in[14];
  const float* bh2 = (const float*)d_in[15];
  float* out = (float*)d_out;

  // workspace layout
  float* ws = (float*)d_ws;
  float* B = ws;                                   // N*256 fp32 (hw)
  u16* Ahi = (u16*)(B + (size_t)N * 256);          // N*256 bf16-hi (reused: EAh N*64)
  u16* Alo = Ahi + (size_t)N * 256;                // N*256 bf16-lo (reused: EAl N*64)
  u16* WTh = Alo + (size_t)N * 256;                // 131072
  u16* WTl = WTh + 131072;                         // 131072
  u16* Hh = WTl + 131072;                          // 8192 (Wh1 tail [128][64])
  u16* Hl = Hh + 8192;                             // 8192
  float* dinv = (float*)(Hl + 8192);               // N
  float* csr_w = dinv + N;                         // E
  int* csr_src = (int*)(csr_w + E);                // E
  int* counts = csr_src + E;                       // N
  int* fill = counts + N;                          // N
  int* rowstart = fill + N;                        // N+1
  int* newidx = rowstart + N + 2;                  // N
  int* nodelist = newidx + N;                      // N
  int* blocksum = nodelist + N;                    // 256
  int* NmInt = blocksum + 256;                     // 1
  float* pooled = (float*)(NmInt + 1);             // 192
  float* phead = pooled + F3;                      // 128
  float* gw = phead + FH;                          // 128
  float* hcst = gw + FH;                           // 1
  float* mcnt = hcst + 1;                          // 1
  (void)ws_size; (void)n_in; (void)out_size;

  u16* W1Th = WTh,        * W1Tl = WTl;
  u16* W2Th = WTh + 16384,  * W2Tl = WTl + 16384;
  u16* W3Th = WTh + 81920,  * W3Tl = WTl + 81920;

  const int rowBlocks = (N + 127) / 128;
  const int aggBlocks = (N + 3) / 4;
  const int scanBlocks = (N + 1023) / 1024;

  init_kernel<<<256, 256, 0, stream>>>(counts, pooled, N);
  // mask scan: newidx/nodelist/Nm/mcnt
  scan_p1<0><<<scanBlocks, 256, 0, stream>>>(nt, blocksum, N);
  scan_p2<<<1, 64, 0, stream>>>(blocksum, scanBlocks);
  scan_p3<0><<<scanBlocks, 256, 0, stream>>>(nt, blocksum, newidx, nodelist, NmInt, mcnt, N);
  count_kernel<<<1024, 256, 0, stream>>>(ei, nt, newidx, counts, E);
  dinv_kernel<<<256, 256, 0, stream>>>(counts, dinv, NmInt);
  // counts scan: rowstart/fill
  scan_p1<1><<<scanBlocks, 256, 0, stream>>>(counts, blocksum, N);
  scan_p2<<<1, 64, 0, stream>>>(blocksum, scanBlocks);
  scan_p3<1><<<scanBlocks, 256, 0, stream>>>(counts, blocksum, rowstart, fill, NmInt, mcnt, N);
  fill_kernel<<<1024, 256, 0, stream>>>(ei, nt, newidx, dinv, fill, csr_src, csr_w, E);
  wsplit_kernel<<<(HDIM * F1 + 255) / 256, 256, 0, stream>>>(W1, W1Th, W1Tl, HDIM, F1);
  wsplit_kernel<<<(F1 * F1 + 255) / 256, 256, 0, stream>>>(W2, W2Th, W2Tl, F1, F1);
  wsplit_kernel<<<(F1 * F3 + 255) / 256, 256, 0, stream>>>(W3, W3Th, W3Tl, F1, F3);
  wsplit_kernel<<<(HDIM * FH + 255) / 256, 256, 0, stream>>>(Wh1 + F3 * FH, Hh, Hl, HDIM, FH);
  embed_split_kernel<<<1024, 256, 0, stream>>>(nodelist, emb, Ahi, Alo, NmInt);

  // layer 1
  gemm_split_kernel<HDIM, F1><<<dim3(rowBlocks, F1 / 64), 256, 0, stream>>>(Ahi, Alo, W1Th, W1Tl, B, NmInt);
  aggregate_split_kernel<F1><<<aggBlocks, 256, 0, stream>>>(B, rowstart, csr_src, csr_w, dinv, b1, Ahi, Alo, NmInt);

  // layer 2
  gemm_split_kernel<F1, F1><<<dim3(rowBlocks, F1 / 64), 256, 0, stream>>>(Ahi, Alo, W2Th, W2Tl, B, NmInt);
  aggregate_split_kernel<F1><<<aggBlocks, 256, 0, stream>>>(B, rowstart, csr_src, csr_w, dinv, b2, Ahi, Alo, NmInt);

  // layer 3 (+ fused masked pool; z3 never materialized)
  gemm_split_kernel<F1, F3><<<dim3(rowBlocks, F3 / 64), 256, 0, stream>>>(Ahi, Alo, W3Th, W3Tl, B, NmInt);
  // Ahi/Alo now dead -> reuse as full-N emb split for the head (row stride 64)
  embed_split_all_kernel<<<1024, 256, 0, stream>>>(x, emb, Ahi, Alo, N);
  agg3_pool_kernel<<<1024, 256, 0, stream>>>(B, rowstart, csr_src, csr_w, dinv, b3, pooled, NmInt);

  // head
  phead_kernel<<<1, 128, 0, stream>>>(pooled, mcnt, Wh1, bh1, gamma, beta, Wh2, bh2, phead, gw, hcst);
  head_mfma_kernel<<<rowBlocks, 256, 0, stream>>>(Ahi, Alo, Hh, Hl, phead, gw, hcst, out, N);
}

// Round 7
// 252.699 us; speedup vs baseline: 11.3752x; 1.1481x over previous
//
#include <hip/hip_runtime.h>

#define HDIM 64
#define F1 256
#define F3 192
#define FH 128

typedef unsigned short u16;
typedef __attribute__((ext_vector_type(8))) short short8;
typedef __attribute__((ext_vector_type(4))) float f32x4;
typedef __attribute__((ext_vector_type(2))) unsigned int uint2v;

// fp32 -> bf16(hi) + bf16(lo), both RNE
__device__ __forceinline__ void split2(float v, u16& h, u16& l) {
  unsigned u = __float_as_uint(v);
  unsigned r = u + 0x7FFFu + ((u >> 16) & 1u);
  h = (u16)(r >> 16);
  float fh = __uint_as_float(((unsigned)h) << 16);
  float res = v - fh;
  unsigned u2 = __float_as_uint(res);
  unsigned r2 = u2 + 0x7FFFu + ((u2 >> 16) & 1u);
  l = (u16)(r2 >> 16);
}

// ---------------- init ----------------
__global__ __launch_bounds__(256) void init_kernel(int* counts, float* pooled, int N) {
  int i = blockIdx.x * blockDim.x + threadIdx.x;
  int stride = gridDim.x * blockDim.x;
  for (int j = i; j < N; j += stride) counts[j] = 0;
  if (i < F3) pooled[i] = 0.0f;
}

// ------------- generic 3-phase exclusive scan, MODE 0: mask(nt==0), 1: counts ----
template <int MODE>
__global__ __launch_bounds__(256) void scan_p1(const int* __restrict__ in,
                                               int* __restrict__ blocksum, int N) {
  __shared__ int wsum[4];
  int base = blockIdx.x * 1024 + threadIdx.x * 4;
  int s = 0;
#pragma unroll
  for (int j = 0; j < 4; ++j) {
    int i = base + j;
    if (i < N) s += (MODE == 0) ? (in[i] == 0 ? 1 : 0) : in[i];
  }
#pragma unroll
  for (int off = 32; off; off >>= 1) s += __shfl_xor(s, off);
  if ((threadIdx.x & 63) == 0) wsum[threadIdx.x >> 6] = s;
  __syncthreads();
  if (threadIdx.x == 0)
    blocksum[blockIdx.x] = wsum[0] + wsum[1] + wsum[2] + wsum[3];
}

__global__ __launch_bounds__(64) void scan_p2(int* __restrict__ blocksum, int G) {
  int tid = threadIdx.x;
  int run = 0;
  for (int b0 = 0; b0 < G; b0 += 64) {
    int i = b0 + tid;
    int orig = (i < G) ? blocksum[i] : 0;
    int v = orig;
#pragma unroll
    for (int off = 1; off < 64; off <<= 1) {
      int t = __shfl_up(v, off);
      if (tid >= off) v += t;
    }
    if (i < G) blocksum[i] = run + v - orig;
    run += __shfl(v, 63);
  }
}

// MODE 0: out0=newidx, out1=nodelist, writes NmInt/mcnt.  MODE 1: out0=rowstart, out1=fill.
template <int MODE>
__global__ __launch_bounds__(256) void scan_p3(const int* __restrict__ in,
                                               const int* __restrict__ blocksum,
                                               int* __restrict__ out0,
                                               int* __restrict__ out1,
                                               int* __restrict__ NmInt,
                                               float* __restrict__ mcnt, int N) {
  __shared__ int wsum[4];
  const int tid = threadIdx.x;
  int base = blockIdx.x * 1024 + tid * 4;
  int c[4];
  int tsum = 0;
#pragma unroll
  for (int j = 0; j < 4; ++j) {
    int i = base + j;
    c[j] = (i < N) ? ((MODE == 0) ? (in[i] == 0 ? 1 : 0) : in[i]) : 0;
    tsum += c[j];
  }
  int v = tsum;
#pragma unroll
  for (int off = 1; off < 64; off <<= 1) {
    int t = __shfl_up(v, off);
    if ((tid & 63) >= off) v += t;
  }
  int wexcl = v - tsum;
  if ((tid & 63) == 63) wsum[tid >> 6] = v;
  __syncthreads();
  int wbase = 0;
  int wv = tid >> 6;
#pragma unroll
  for (int j = 0; j < 4; ++j)
    if (j < wv) wbase += wsum[j];
  int off0 = blocksum[blockIdx.x] + wbase + wexcl;
#pragma unroll
  for (int j = 0; j < 4; ++j) {
    int i = base + j;
    if (i < N) {
      if (MODE == 0) {
        out0[i] = off0;
        if (c[j]) out1[off0] = i;
        off0 += c[j];
        if (i == N - 1) { *NmInt = off0; *mcnt = (float)off0; }
      } else {
        out0[i] = off0;
        out1[i] = off0;
        off0 += c[j];
        if (i == N - 1) out0[N] = off0;
      }
    }
  }
}

// ---------------- masked in-degree in COMPACTED dst space ----------------
__global__ __launch_bounds__(256) void count_kernel(const int* __restrict__ ei,
                                                    const int* __restrict__ nt,
                                                    const int* __restrict__ newidx,
                                                    int* __restrict__ counts, int E) {
  int i = blockIdx.x * blockDim.x + threadIdx.x;
  int stride = gridDim.x * blockDim.x;
  for (int e = i; e < E; e += stride) {
    int s = ei[e], d = ei[E + e];
    if (nt[s] == 0 && nt[d] == 0) atomicAdd(&counts[newidx[d]], 1);
  }
}

// ---------------- counts -> dinv (compacted) ----------------
__global__ __launch_bounds__(256) void dinv_kernel(const int* __restrict__ counts,
                                                   float* __restrict__ dinv,
                                                   const int* __restrict__ NmPtr) {
  int Nm = *NmPtr;
  int i = blockIdx.x * blockDim.x + threadIdx.x;
  int stride = gridDim.x * blockDim.x;
  for (int j = i; j < Nm; j += stride) dinv[j] = rsqrtf(1.0f + (float)counts[j]);
}

// ---------------- bucket active edges by compacted dst ----------------
__global__ __launch_bounds__(256) void fill_kernel(const int* __restrict__ ei,
                                                   const int* __restrict__ nt,
                                                   const int* __restrict__ newidx,
                                                   const float* __restrict__ dinv,
                                                   int* __restrict__ fill,
                                                   int* __restrict__ csr_src,
                                                   float* __restrict__ csr_w, int E) {
  int i = blockIdx.x * blockDim.x + threadIdx.x;
  int stride = gridDim.x * blockDim.x;
  for (int e = i; e < E; e += stride) {
    int s = ei[e], d = ei[E + e];
    if (nt[s] == 0 && nt[d] == 0) {
      int ns = newidx[s], nd = newidx[d];
      int pos = atomicAdd(&fill[nd], 1);
      csr_src[pos] = ns;
      csr_w[pos] = dinv[ns] * dinv[nd];
    }
  }
}

// ---------------- pre-split + transpose weights ----------------
__global__ __launch_bounds__(256) void wsplit_kernel(const float* __restrict__ W,
                                                     u16* __restrict__ Th,
                                                     u16* __restrict__ Tl,
                                                     int FIN, int FOUT) {
  int i = blockIdx.x * blockDim.x + threadIdx.x;
  if (i >= FIN * FOUT) return;
  int k = i / FOUT, c = i % FOUT;
  u16 h, l;
  split2(W[i], h, l);
  Th[(size_t)c * FIN + k] = h;
  Tl[(size_t)c * FIN + k] = l;
}

// ---------------- z0c[r] = emb[nodelist[r]] (fp32 compacted) ----------------
__global__ __launch_bounds__(256) void z0c_kernel(const int* __restrict__ nodelist,
                                                  const float* __restrict__ emb,
                                                  float* __restrict__ z0c,
                                                  const int* __restrict__ NmPtr) {
  int Nm = *NmPtr;
  int i = blockIdx.x * blockDim.x + threadIdx.x;
  int stride = gridDim.x * blockDim.x;
  int total = Nm * (HDIM / 4);
  for (int j = i; j < total; j += stride) {
    int row = j >> 4;
    int c = (j & 15) * 4;
    int xr = nodelist[row];
    *(float4*)&z0c[(size_t)row * HDIM + c] = *(const float4*)&emb[(size_t)xr * HDIM + c];
  }
}

// ---- full-N emb split for head (into reused fp32 buffer region) ----
__global__ __launch_bounds__(256) void embed_split_all_kernel(const int* __restrict__ idx,
                                                              const float* __restrict__ emb,
                                                              u16* __restrict__ Ah,
                                                              u16* __restrict__ Al, int N) {
  int i = blockIdx.x * blockDim.x + threadIdx.x;
  int stride = gridDim.x * blockDim.x;
  int total = N * (HDIM / 4);
  for (int j = i; j < total; j += stride) {
    int row = j >> 4;
    int c = (j & 15) * 4;
    int xr = idx[row];
    float4 v = *(const float4*)&emb[(size_t)xr * HDIM + c];
    u16 h0, l0, h1, l1, h2, l2, h3, l3;
    split2(v.x, h0, l0); split2(v.y, h1, l1);
    split2(v.z, h2, l2); split2(v.w, h3, l3);
    uint2v hp = {(unsigned)h0 | ((unsigned)h1 << 16), (unsigned)h2 | ((unsigned)h3 << 16)};
    uint2v lp = {(unsigned)l0 | ((unsigned)l1 << 16), (unsigned)l2 | ((unsigned)l3 << 16)};
    *(uint2v*)&Ah[(size_t)row * HDIM + c] = hp;
    *(uint2v*)&Al[(size_t)row * HDIM + c] = lp;
  }
}

// ---- input-side aggregation, 64-dim: G = A_hat @ z0c, split output ----
__global__ __launch_bounds__(256) void agg64_kernel(
    const float* __restrict__ z0c, const int* __restrict__ rowstart,
    const int* __restrict__ csr_src, const float* __restrict__ csr_w,
    const float* __restrict__ dinv,
    u16* __restrict__ Ah, u16* __restrict__ Al, const int* __restrict__ NmPtr) {
  const int Nm = *NmPtr;
  const int lane = threadIdx.x & 63;
  const int wid = (int)((blockIdx.x * blockDim.x + threadIdx.x) >> 6);
  const int nw = (int)((gridDim.x * blockDim.x) >> 6);
  for (int r = wid; r < Nm; r += nw) {
    const int e0 = rowstart[r];
    const int e1 = rowstart[r + 1];
    float di = dinv[r];
    float acc = di * di * z0c[(size_t)r * HDIM + lane];
    for (int eb = e0; eb < e1; eb += 8) {
      int s[8]; float w[8];
#pragma unroll
      for (int u = 0; u < 8; ++u) {
        int idx = eb + u;
        bool ok = idx < e1;
        s[u] = ok ? csr_src[idx] : r;
        w[u] = ok ? csr_w[idx] : 0.f;
      }
      float v[8];
#pragma unroll
      for (int u = 0; u < 8; ++u) v[u] = z0c[(size_t)s[u] * HDIM + lane];
#pragma unroll
      for (int u = 0; u < 8; ++u) acc += w[u] * v[u];
    }
    u16 h, l;
    split2(acc, h, l);
    Ah[(size_t)r * HDIM + lane] = h;
    Al[(size_t)r * HDIM + lane] = l;
  }
}

// ---- input-side aggregation, 256-dim: G = A_hat @ Z (fp32 in), split output ----
__global__ __launch_bounds__(256) void agg256_kernel(
    const float* __restrict__ Z, const int* __restrict__ rowstart,
    const int* __restrict__ csr_src, const float* __restrict__ csr_w,
    const float* __restrict__ dinv,
    u16* __restrict__ Ah, u16* __restrict__ Al, const int* __restrict__ NmPtr) {
  const int Nm = *NmPtr;
  const int lane = threadIdx.x & 63;
  const int wid = (int)((blockIdx.x * blockDim.x + threadIdx.x) >> 6);
  const int nw = (int)((gridDim.x * blockDim.x) >> 6);
  for (int r = wid; r < Nm; r += nw) {
    const int e0 = rowstart[r];
    const int e1 = rowstart[r + 1];
    float di = dinv[r];
    float sn = di * di;
    float4 sv = *(const float4*)&Z[(size_t)r * F1 + 4 * lane];
    float4 acc = {sn * sv.x, sn * sv.y, sn * sv.z, sn * sv.w};
    for (int eb = e0; eb < e1; eb += 8) {
      int s[8]; float w[8];
#pragma unroll
      for (int u = 0; u < 8; ++u) {
        int idx = eb + u;
        bool ok = idx < e1;
        s[u] = ok ? csr_src[idx] : r;
        w[u] = ok ? csr_w[idx] : 0.f;
      }
      float4 v[8];
#pragma unroll
      for (int u = 0; u < 8; ++u) v[u] = *(const float4*)&Z[(size_t)s[u] * F1 + 4 * lane];
#pragma unroll
      for (int u = 0; u < 8; ++u) {
        acc.x += w[u] * v[u].x; acc.y += w[u] * v[u].y;
        acc.z += w[u] * v[u].z; acc.w += w[u] * v[u].w;
      }
    }
    u16 h0, l0, h1, l1, h2, l2, h3, l3;
    split2(acc.x, h0, l0); split2(acc.y, h1, l1);
    split2(acc.z, h2, l2); split2(acc.w, h3, l3);
    uint2v hp = {(unsigned)h0 | ((unsigned)h1 << 16), (unsigned)h2 | ((unsigned)h3 << 16)};
    uint2v lp = {(unsigned)l0 | ((unsigned)l1 << 16), (unsigned)l2 | ((unsigned)l3 << 16)};
    *(uint2v*)&Ah[(size_t)r * F1 + 4 * lane] = hp;
    *(uint2v*)&Al[(size_t)r * F1 + 4 * lane] = lp;
  }
}

// ------- split-bf16 MFMA GEMM over compacted rows.
// MODE 1: Out = relu(acc + bias) stored fp32.  MODE 2: pooled += sum_rows relu(acc+bias), no store.
template <int FIN, int FOUT, int MODE>
__global__ __launch_bounds__(256) void gemm_split_kernel(const u16* __restrict__ Ah,
                                                         const u16* __restrict__ Al,
                                                         const u16* __restrict__ Wh,
                                                         const u16* __restrict__ Wl,
                                                         const float* __restrict__ bias,
                                                         float* __restrict__ Out,
                                                         float* __restrict__ pooled,
                                                         const int* __restrict__ NmPtr) {
  const int Nm = *NmPtr;
  const int r0 = blockIdx.x * 128, c0 = blockIdx.y * 64;
  if (r0 >= Nm) return;
  __shared__ u16 AH[8 * 128 * 8], AL[8 * 128 * 8];
  __shared__ u16 WH[8 * 64 * 8], WL[8 * 64 * 8];
  const int tid = threadIdx.x;
  const int lane = tid & 63, w = tid >> 6;
  const int l15 = lane & 15, l4 = lane >> 4;
  f32x4 acc[2][4] = {};

  for (int k0 = 0; k0 < FIN; k0 += 64) {
#pragma unroll
    for (int p = 0; p < 4; ++p) {
      int e = p * 2048 + tid * 8;
      int r = e >> 6, ke = e & 63;
      int g0 = ke >> 2;
      int h = (g0 >> 2) & 1;
      int gp = (g0 & 3) | ((g0 >> 3) << 2);
      uint2v vh0 = {0, 0}, vh1 = {0, 0}, vl0 = {0, 0}, vl1 = {0, 0};
      if (r0 + r < Nm) {
        size_t gbase = (size_t)(r0 + r) * FIN + k0 + ke;
        vh0 = *(const uint2v*)&Ah[gbase];
        vh1 = *(const uint2v*)&Ah[gbase + 4];
        vl0 = *(const uint2v*)&Al[gbase];
        vl1 = *(const uint2v*)&Al[gbase + 4];
      }
      *(uint2v*)&AH[((gp * 128 + r) * 8) + h * 4] = vh0;
      *(uint2v*)&AH[(((gp + 1) * 128 + r) * 8) + h * 4] = vh1;
      *(uint2v*)&AL[((gp * 128 + r) * 8) + h * 4] = vl0;
      *(uint2v*)&AL[(((gp + 1) * 128 + r) * 8) + h * 4] = vl1;
    }
#pragma unroll
    for (int p = 0; p < 2; ++p) {
      int e = p * 2048 + tid * 8;
      int c = e >> 6, ke = e & 63;
      int g0 = ke >> 2;
      int h = (g0 >> 2) & 1;
      int gp = (g0 & 3) | ((g0 >> 3) << 2);
      size_t gbase = (size_t)(c0 + c) * FIN + k0 + ke;
      uint2v vh0 = *(const uint2v*)&Wh[gbase];
      uint2v vh1 = *(const uint2v*)&Wh[gbase + 4];
      uint2v vl0 = *(const uint2v*)&Wl[gbase];
      uint2v vl1 = *(const uint2v*)&Wl[gbase + 4];
      *(uint2v*)&WH[((gp * 64 + c) * 8) + h * 4] = vh0;
      *(uint2v*)&WH[(((gp + 1) * 64 + c) * 8) + h * 4] = vh1;
      *(uint2v*)&WL[((gp * 64 + c) * 8) + h * 4] = vl0;
      *(uint2v*)&WL[(((gp + 1) * 64 + c) * 8) + h * 4] = vl1;
    }
    __syncthreads();
#pragma unroll
    for (int ko = 0; ko < 2; ++ko) {
      const int gb = ko * 4 + l4;
      short8 ah[2], al[2], wh[4], wl[4];
#pragma unroll
      for (int mi = 0; mi < 2; ++mi) {
        int slot = gb * 128 + (w * 32 + mi * 16 + l15);
        ah[mi] = *(const short8*)&AH[slot * 8];
        al[mi] = *(const short8*)&AL[slot * 8];
      }
#pragma unroll
      for (int ni = 0; ni < 4; ++ni) {
        int slot = gb * 64 + (ni * 16 + l15);
        wh[ni] = *(const short8*)&WH[slot * 8];
        wl[ni] = *(const short8*)&WL[slot * 8];
      }
#pragma unroll
      for (int mi = 0; mi < 2; ++mi)
#pragma unroll
        for (int ni = 0; ni < 4; ++ni) {
          acc[mi][ni] = __builtin_amdgcn_mfma_f32_16x16x32_bf16(ah[mi], wh[ni], acc[mi][ni], 0, 0, 0);
          acc[mi][ni] = __builtin_amdgcn_mfma_f32_16x16x32_bf16(ah[mi], wl[ni], acc[mi][ni], 0, 0, 0);
          acc[mi][ni] = __builtin_amdgcn_mfma_f32_16x16x32_bf16(al[mi], wh[ni], acc[mi][ni], 0, 0, 0);
        }
    }
    __syncthreads();
  }

  float bb[4];
#pragma unroll
  for (int ni = 0; ni < 4; ++ni) bb[ni] = bias[c0 + ni * 16 + l15];

  if (MODE == 1) {
#pragma unroll
    for (int mi = 0; mi < 2; ++mi)
#pragma unroll
      for (int ni = 0; ni < 4; ++ni)
#pragma unroll
        for (int j = 0; j < 4; ++j) {
          int row = r0 + w * 32 + mi * 16 + l4 * 4 + j;
          if (row < Nm)
            Out[(size_t)row * FOUT + c0 + ni * 16 + l15] =
                fmaxf(acc[mi][ni][j] + bb[ni], 0.f);
        }
  } else {
    __shared__ float wred[4][64];
    float part[4] = {0.f, 0.f, 0.f, 0.f};
#pragma unroll
    for (int mi = 0; mi < 2; ++mi)
#pragma unroll
      for (int ni = 0; ni < 4; ++ni)
#pragma unroll
        for (int j = 0; j < 4; ++j) {
          int row = r0 + w * 32 + mi * 16 + l4 * 4 + j;
          if (row < Nm) part[ni] += fmaxf(acc[mi][ni][j] + bb[ni], 0.f);
        }
#pragma unroll
    for (int ni = 0; ni < 4; ++ni) {
      part[ni] += __shfl_xor(part[ni], 16);
      part[ni] += __shfl_xor(part[ni], 32);
    }
    if (l4 == 0)
#pragma unroll
      for (int ni = 0; ni < 4; ++ni) wred[w][ni * 16 + l15] = part[ni];
    __syncthreads();
    if (tid < 64) {
      float s = wred[0][tid] + wred[1][tid] + wred[2][tid] + wred[3][tid];
      atomicAdd(&pooled[c0 + tid], s);
    }
  }
}

// ------- phead = bh1 + (pooled/mcnt) @ Wh1[0:192,:]; also gw, hcst -------
__global__ __launch_bounds__(128) void phead_kernel(const float* __restrict__ pooled,
                                                    const float* __restrict__ mcnt,
                                                    const float* __restrict__ Wh1,
                                                    const float* __restrict__ bh1,
                                                    const float* __restrict__ gamma,
                                                    const float* __restrict__ beta,
                                                    const float* __restrict__ Wh2,
                                                    const float* __restrict__ bh2,
                                                    float* __restrict__ phead,
                                                    float* __restrict__ gw,
                                                    float* __restrict__ hcst) {
  int t = threadIdx.x;
  float inv = 1.0f / *mcnt;
  float acc = bh1[t];
  for (int k = 0; k < F3; ++k) acc += pooled[k] * inv * Wh1[k * FH + t];
  phead[t] = acc;
  const float bninv = 1.0f / sqrtf(1.0f + 1e-5f);
  float w2 = Wh2[t];
  gw[t] = gamma[t] * bninv * w2;
  __shared__ float red[FH];
  red[t] = beta[t] * w2;
  __syncthreads();
  if (t == 0) {
    float s = bh2[0];
    for (int i = 0; i < FH; ++i) s += red[i];
    *hcst = s;
  }
}

// ---- MFMA head ----
__global__ __launch_bounds__(256) void head_mfma_kernel(
    const u16* __restrict__ EAh, const u16* __restrict__ EAl,
    const u16* __restrict__ Hh, const u16* __restrict__ Hl,
    const float* __restrict__ phead, const float* __restrict__ gw,
    const float* __restrict__ hcst, float* __restrict__ out, int N) {
  const int tid = threadIdx.x;
  const int lane = tid & 63, w = tid >> 6;
  const int l15 = lane & 15, l4 = lane >> 4;
  const int r0 = blockIdx.x * 128;
  f32x4 acc[2][8] = {};
  const short8 zfrag = {};

#pragma unroll
  for (int ko = 0; ko < 2; ++ko) {
    const int kb = 32 * ko + 4 * l4;
    short8 bh[8], bl[8], ah[2], al[2];
#pragma unroll
    for (int ni = 0; ni < 8; ++ni) {
      int col = ni * 16 + l15;
      const u16* p = &Hh[col * 64 + kb];
      ((uint2v*)&bh[ni])[0] = *(const uint2v*)p;
      ((uint2v*)&bh[ni])[1] = *(const uint2v*)(p + 16);
      const u16* q = &Hl[col * 64 + kb];
      ((uint2v*)&bl[ni])[0] = *(const uint2v*)q;
      ((uint2v*)&bl[ni])[1] = *(const uint2v*)(q + 16);
    }
#pragma unroll
    for (int mi = 0; mi < 2; ++mi) {
      int row = r0 + w * 32 + mi * 16 + l15;
      if (row < N) {
        const u16* p = &EAh[(size_t)row * 64 + kb];
        ((uint2v*)&ah[mi])[0] = *(const uint2v*)p;
        ((uint2v*)&ah[mi])[1] = *(const uint2v*)(p + 16);
        const u16* q = &EAl[(size_t)row * 64 + kb];
        ((uint2v*)&al[mi])[0] = *(const uint2v*)q;
        ((uint2v*)&al[mi])[1] = *(const uint2v*)(q + 16);
      } else {
        ah[mi] = zfrag;
        al[mi] = zfrag;
      }
    }
#pragma unroll
    for (int mi = 0; mi < 2; ++mi)
#pragma unroll
      for (int ni = 0; ni < 8; ++ni) {
        acc[mi][ni] = __builtin_amdgcn_mfma_f32_16x16x32_bf16(ah[mi], bh[ni], acc[mi][ni], 0, 0, 0);
        acc[mi][ni] = __builtin_amdgcn_mfma_f32_16x16x32_bf16(ah[mi], bl[ni], acc[mi][ni], 0, 0, 0);
        acc[mi][ni] = __builtin_amdgcn_mfma_f32_16x16x32_bf16(al[mi], bh[ni], acc[mi][ni], 0, 0, 0);
      }
  }

  const float hc = *hcst;
  float ph[8], g[8];
#pragma unroll
  for (int ni = 0; ni < 8; ++ni) {
    int col = ni * 16 + l15;
    ph[ni] = phead[col];
    g[ni] = gw[col];
  }
#pragma unroll
  for (int mi = 0; mi < 2; ++mi)
#pragma unroll
    for (int j = 0; j < 4; ++j) {
      float s = 0.f;
#pragma unroll
      for (int ni = 0; ni < 8; ++ni)
        s += fmaxf(acc[mi][ni][j] + ph[ni], 0.f) * g[ni];
#pragma unroll
      for (int off = 1; off < 16; off <<= 1) s += __shfl_xor(s, off);
      int row = r0 + w * 32 + mi * 16 + l4 * 4 + j;
      if (l15 == 0 && row < N) out[row] = s + hc;
    }
}

extern "C" void kernel_launch(void* const* d_in, const int* in_sizes, int n_in,
                              void* d_out, int out_size, void* d_ws, size_t ws_size,
                              hipStream_t stream) {
  const int N = in_sizes[0];
  const int E = in_sizes[1] / 2;

  const int* x = (const int*)d_in[0];
  const int* ei = (const int*)d_in[1];
  const int* nt = (const int*)d_in[2];
  const float* emb = (const float*)d_in[3];
  const float* W1 = (const float*)d_in[4];
  const float* b1 = (const float*)d_in[5];
  const float* W2 = (const float*)d_in[6];
  const float* b2 = (const float*)d_in[7];
  const float* W3 = (const float*)d_in[8];
  const float* b3 = (const float*)d_in[9];
  const float* Wh1 = (const float*)d_in[10];
  const float* bh1 = (const float*)d_in[11];
  const float* gamma = (const float*)d_in[12];
  const float* beta = (const float*)d_in[13];
  const float* Wh2 = (const float*)d_in[14];
  const float* bh2 = (const float*)d_in[15];
  float* out = (float*)d_out;

  // workspace layout
  float* ws = (float*)d_ws;
  float* B = ws;                                   // N*256 fp32 (z1/z2; later head emb split u16)
  u16* Ahi = (u16*)(B + (size_t)N * 256);          // N*256 u16 (aggregated split hi)
  u16* Alo = Ahi + (size_t)N * 256;                // N*256 u16
  u16* WTh = Alo + (size_t)N * 256;                // 131072
  u16* WTl = WTh + 131072;                         // 131072
  u16* Hh = WTl + 131072;                          // 8192 (Wh1 tail [128][64])
  u16* Hl = Hh + 8192;                             // 8192
  float* z0c = (float*)(Hl + 8192);                // N*64 fp32 compacted emb
  float* dinv = z0c + (size_t)N * HDIM;            // N
  float* csr_w = dinv + N;                         // E
  int* csr_src = (int*)(csr_w + E);                // E
  int* counts = csr_src + E;                       // N
  int* fill = counts + N;                          // N
  int* rowstart = fill + N;                        // N+1
  int* newidx = rowstart + N + 2;                  // N
  int* nodelist = newidx + N;                      // N
  int* blocksum = nodelist + N;                    // 256
  int* NmInt = blocksum + 256;                     // 1
  float* pooled = (float*)(NmInt + 1);             // 192
  float* phead = pooled + F3;                      // 128
  float* gw = phead + FH;                          // 128
  float* hcst = gw + FH;                           // 1
  float* mcnt = hcst + 1;                          // 1
  (void)ws_size; (void)n_in; (void)out_size;

  u16* W1Th = WTh,        * W1Tl = WTl;
  u16* W2Th = WTh + 16384,  * W2Tl = WTl + 16384;
  u16* W3Th = WTh + 81920,  * W3Tl = WTl + 81920;
  u16* EAh = (u16*)B;                              // head emb split (after z2 dead)
  u16* EAl = EAh + (size_t)N * HDIM;

  const int rowBlocks = (N + 127) / 128;
  const int aggBlocks = (N + 3) / 4;
  const int scanBlocks = (N + 1023) / 1024;

  init_kernel<<<256, 256, 0, stream>>>(counts, pooled, N);
  // mask scan: newidx/nodelist/Nm/mcnt
  scan_p1<0><<<scanBlocks, 256, 0, stream>>>(nt, blocksum, N);
  scan_p2<<<1, 64, 0, stream>>>(blocksum, scanBlocks);
  scan_p3<0><<<scanBlocks, 256, 0, stream>>>(nt, blocksum, newidx, nodelist, NmInt, mcnt, N);
  count_kernel<<<1024, 256, 0, stream>>>(ei, nt, newidx, counts, E);
  dinv_kernel<<<256, 256, 0, stream>>>(counts, dinv, NmInt);
  // counts scan: rowstart/fill
  scan_p1<1><<<scanBlocks, 256, 0, stream>>>(counts, blocksum, N);
  scan_p2<<<1, 64, 0, stream>>>(blocksum, scanBlocks);
  scan_p3<1><<<scanBlocks, 256, 0, stream>>>(counts, blocksum, rowstart, fill, NmInt, mcnt, N);
  fill_kernel<<<1024, 256, 0, stream>>>(ei, nt, newidx, dinv, fill, csr_src, csr_w, E);
  wsplit_kernel<<<(HDIM * F1 + 255) / 256, 256, 0, stream>>>(W1, W1Th, W1Tl, HDIM, F1);
  wsplit_kernel<<<(F1 * F1 + 255) / 256, 256, 0, stream>>>(W2, W2Th, W2Tl, F1, F1);
  wsplit_kernel<<<(F1 * F3 + 255) / 256, 256, 0, stream>>>(W3, W3Th, W3Tl, F1, F3);
  wsplit_kernel<<<(HDIM * FH + 255) / 256, 256, 0, stream>>>(Wh1 + F3 * FH, Hh, Hl, HDIM, FH);
  z0c_kernel<<<1024, 256, 0, stream>>>(nodelist, emb, z0c, NmInt);

  // layer 1: input-side agg on 64-dim z0c, then GEMM with fused bias+relu
  agg64_kernel<<<aggBlocks, 256, 0, stream>>>(z0c, rowstart, csr_src, csr_w, dinv, Ahi, Alo, NmInt);
  gemm_split_kernel<HDIM, F1, 1><<<dim3(rowBlocks, F1 / 64), 256, 0, stream>>>(
      Ahi, Alo, W1Th, W1Tl, b1, B, nullptr, NmInt);

  // layer 2: input-side agg on z1 (fp32), GEMM fused bias+relu
  agg256_kernel<<<aggBlocks, 256, 0, stream>>>(B, rowstart, csr_src, csr_w, dinv, Ahi, Alo, NmInt);
  gemm_split_kernel<F1, F1, 1><<<dim3(rowBlocks, F1 / 64), 256, 0, stream>>>(
      Ahi, Alo, W2Th, W2Tl, b2, B, nullptr, NmInt);

  // layer 3: input-side agg on z2, GEMM with fused bias+relu+POOL (z3 never stored)
  agg256_kernel<<<aggBlocks, 256, 0, stream>>>(B, rowstart, csr_src, csr_w, dinv, Ahi, Alo, NmInt);
  embed_split_all_kernel<<<1024, 256, 0, stream>>>(x, emb, EAh, EAl, N);  // B (z2) dead now
  gemm_split_kernel<F1, F3, 2><<<dim3(rowBlocks, F3 / 64), 256, 0, stream>>>(
      Ahi, Alo, W3Th, W3Tl, b3, nullptr, pooled, NmInt);

  // head
  phead_kernel<<<1, 128, 0, stream>>>(pooled, mcnt, Wh1, bh1, gamma, beta, Wh2, bh2, phead, gw, hcst);
  head_mfma_kernel<<<rowBlocks, 256, 0, stream>>>(EAh, EAl, Hh, Hl, phead, gw, hcst, out, N);
}